// Round 4
// baseline (209.050 us; speedup 1.0000x reference)
//
#include <hip/hip_runtime.h>
#include <math.h>

#define TT 2048
#define CDIM 1024
#define KAUG 1088
#define BT 4096
#define NTILES 17   // KAUG / 64

typedef __attribute__((ext_vector_type(8))) short bf16x8;
typedef __attribute__((ext_vector_type(4))) short short4v;
typedef __attribute__((ext_vector_type(4))) float f32x4;
typedef __attribute__((ext_vector_type(16))) float f32x16;

static __device__ __forceinline__ float bf2f(short s) {
  union { unsigned int u; float f; } c;
  c.u = ((unsigned int)(unsigned short)s) << 16;
  return c.f;
}
static __device__ __forceinline__ short f2bf(float f) {
  union { float f; unsigned int u; } c; c.f = f;
  unsigned int u = c.u;
  u += 0x7fff + ((u >> 16) & 1);   // round-to-nearest-even
  return (short)(u >> 16);
}

static __device__ __forceinline__ void gload_lds16(const void* g, void* l) {
  __builtin_amdgcn_global_load_lds(
      (const __attribute__((address_space(1))) void*)g,
      (__attribute__((address_space(3))) void*)l, 16, 0, 0);
}

static __device__ __forceinline__ unsigned int cvt_pk_bf16(float lo, float hi) {
  unsigned int r;
  asm("v_cvt_pk_bf16_f32 %0, %1, %2" : "=v"(r) : "v"(lo), "v"(hi));
  return r;
}

// ---------------------------------------------------------------------------
// rank1: xa = x @ A_attn^T (fp32), fused with packing x -> Xaug (bf16) and
// writing cols [1024,1040) = 2*xa (bf16), [1040,1088) = 0.
__global__ __launch_bounds__(256) void rank1_kernel(
    const float* __restrict__ x, const float* __restrict__ Aattn,
    short* __restrict__ Xaug) {
  __shared__ float xls[16][1024];
  const int tid = threadIdx.x;
  const int row0 = blockIdx.x * 16;
  for (int i = tid; i < 16 * 256; i += 256) {
    int row = i >> 8, c4 = (i & 255) * 4;
    float4 v = *(const float4*)(x + (size_t)(row0 + row) * CDIM + c4);
    *(float4*)&xls[row][c4] = v;
    short4v p;
    p.x = f2bf(v.x); p.y = f2bf(v.y); p.z = f2bf(v.z); p.w = f2bf(v.w);
    *(short4v*)(Xaug + (size_t)(row0 + row) * KAUG + c4) = p;
  }
  __syncthreads();
  const int row = tid >> 4, r = tid & 15;
  float acc = 0.f;
  for (int c = 0; c < 1024; c += 4) {
    float4 a = *(const float4*)(Aattn + (size_t)r * 1024 + c);
    float4 xv = *(const float4*)&xls[row][c];
    acc += a.x * xv.x + a.y * xv.y + a.z * xv.z + a.w * xv.w;
  }
  Xaug[(size_t)(row0 + row) * KAUG + 1024 + r] = f2bf(2.f * acc);
  for (int i = tid; i < 16 * 48; i += 256) {
    int rr = i / 48, cc = 1040 + (i % 48);
    Xaug[(size_t)(row0 + rr) * KAUG + cc] = 0;
  }
}

// ---------------------------------------------------------------------------
// rank2: ca = ctx @ A_proj^T, ctx = Caug cols [0,1024) (bf16, stride KAUG);
// writes Caug cols [1024,1040) = 2*ca (bf16), [1040,1088) = 0.
__global__ __launch_bounds__(256) void rank2_kernel(
    const float* __restrict__ Aproj, short* __restrict__ Caug) {
  __shared__ float cls[16][1024];
  const int tid = threadIdx.x;
  const int row0 = blockIdx.x * 16;
  for (int i = tid; i < 16 * 128; i += 256) {
    int row = i >> 7, c8 = (i & 127) * 8;
    bf16x8 v = *(const bf16x8*)(Caug + (size_t)(row0 + row) * KAUG + c8);
#pragma unroll
    for (int j = 0; j < 8; j++) cls[row][c8 + j] = bf2f(v[j]);
  }
  __syncthreads();
  const int row = tid >> 4, r = tid & 15;
  float acc = 0.f;
  for (int c = 0; c < 1024; c += 4) {
    float4 a = *(const float4*)(Aproj + (size_t)r * 1024 + c);
    float4 xv = *(const float4*)&cls[row][c];
    acc += a.x * xv.x + a.y * xv.y + a.z * xv.z + a.w * xv.w;
  }
  Caug[(size_t)(row0 + row) * KAUG + 1024 + r] = f2bf(2.f * acc);
  for (int i = tid; i < 16 * 48; i += 256) {
    int rr = i / 48, cc = 1040 + (i % 48);
    Caug[(size_t)(row0 + rr) * KAUG + cc] = 0;
  }
}

// ---------------------------------------------------------------------------
// pack W (fp32 [rows][1024]) + Bmat (fp32 [rows][16]) -> Waug bf16 [rows][1088]
__global__ __launch_bounds__(256) void packw_kernel(
    const float* __restrict__ W, const float* __restrict__ Bm,
    short* __restrict__ Waug, int rows) {
  int i = blockIdx.x * 256 + threadIdx.x;
  int total = rows * 136;
  if (i >= total) return;
  int row = i / 136;
  int c8 = (i - row * 136) * 8;
  bf16x8 p;
  if (c8 < 1024) {
    float4 v0 = *(const float4*)(W + (size_t)row * 1024 + c8);
    float4 v1 = *(const float4*)(W + (size_t)row * 1024 + c8 + 4);
    p[0] = f2bf(v0.x); p[1] = f2bf(v0.y); p[2] = f2bf(v0.z); p[3] = f2bf(v0.w);
    p[4] = f2bf(v1.x); p[5] = f2bf(v1.y); p[6] = f2bf(v1.z); p[7] = f2bf(v1.w);
  } else if (c8 < 1040) {
#pragma unroll
    for (int j = 0; j < 8; j++) p[j] = f2bf(Bm[(size_t)row * 16 + (c8 - 1024) + j]);
  } else {
#pragma unroll
    for (int j = 0; j < 8; j++) p[j] = 0;
  }
  *(bf16x8*)(Waug + (size_t)row * KAUG + c8) = p;
}

// ---------------------------------------------------------------------------
// 256x256 bf16 MFMA GEMM, K = KAUG, counted-vmcnt pipelined (T3/T4/T5).
// 512 threads = 8 waves (2 M-halves x 4 N-quarters); per-wave C: 128x64.
// LDS: 2 buffers x {A: 2 halves, B: 2 halves} x [128 rows][64 k] bf16 = 128KB.
// Per K-tile t: 4 phases; phase p computes m-pair {2p,2p+1} x n{0..3} x kk{0,1}
// = 16 MFMA and stages one half-tile of t+1 (2 global_load_lds / thread).
// Sync: (A) = vmcnt(2)+s_barrier at tile start (after issuing first prefetch,
// so the VMEM queue never drains); (B) = s_barrier at tile end (licenses
// overwriting the buffer). Each wave reads only A-half(wr) and B-half(wc>>1).
// EPI 0: QKV epilogue (bias, q*0.125*log2e, fake-quant K/V, K->[bh][t][d],
//        V->transposed [bh][d][t]).  EPI 1: proj epilogue (bias, fp32 out).
template <int EPI>
__global__ __launch_bounds__(512, 2) void gemm256_kernel(
    const short* __restrict__ Amat, const short* __restrict__ Bmat,
    const float* __restrict__ bias,
    const float* __restrict__ kv_scale, const float* __restrict__ kv_zp,
    short* __restrict__ Qb, short* __restrict__ Kb, short* __restrict__ Vt,
    float* __restrict__ Out) {
  __shared__ short lds[65536];   // 128 KB
  const int tid = threadIdx.x;
  const int lane = tid & 63;
  const int w = tid >> 6;
  const int wr = w >> 2, wc = w & 3;
  const int r16 = lane & 15, g = lane >> 4;

  // XCD-aware bijective swizzle (gridDim.x % 8 == 0 for both uses)
  const int nwg = gridDim.x;
  const int cpx = nwg >> 3;
  const int swzb = (blockIdx.x & 7) * cpx + (blockIdx.x >> 3);
  const int bm = (swzb & 15) * 256;
  const int bn = (swzb >> 4) * 256;

  // staging geometry: thread covers chunks (srow, scg) and (srow+64, scg)
  // of a 128x64 half-tile; LDS chunk (r,c) holds global chunk (r, c^(r&7)).
  const int srow = tid >> 3;
  const int scg = (tid & 7) ^ (srow & 7);
  char* const ldsB = (char*)lds;

#define STAGE(mat, row0, k0, slot, buf)                                        \
  do {                                                                         \
    const short* s_ = (mat) + (size_t)((row0) + srow) * KAUG + (k0) + scg * 8; \
    char* d_ = ldsB + (buf) * 65536 + (slot) * 16384 + w * 1024;               \
    gload_lds16(s_, d_);                                                       \
    gload_lds16(s_ + (size_t)64 * KAUG, d_ + 8192);                            \
  } while (0)

  f32x4 zero = {0.f, 0.f, 0.f, 0.f};
  f32x4 acc[8][4];
#pragma unroll
  for (int i = 0; i < 8; i++)
#pragma unroll
    for (int j = 0; j < 4; j++) acc[i][j] = zero;

  // prologue: stage all 4 halves of tile 0 into buffer 0
  STAGE(Amat, bm, 0, 0, 0);
  STAGE(Amat, bm + 128, 0, 1, 0);
  STAGE(Bmat, bn, 0, 2, 0);
  STAGE(Bmat, bn + 128, 0, 3, 0);

  int cur = 0;
  for (int t = 0; t < NTILES; ++t) {
    const int nxt = cur ^ 1;
    const int k1 = (t + 1) * 64;
    const int abase = cur * 65536 + wr * 16384;
    const int bbase = cur * 65536 + (2 + (wc >> 1)) * 16384;
    const int brow0 = (wc & 1) * 64;

    // ---- phase 0: prefetch A-half0(t+1); (A); read B frags + A pair 0
    if (t < NTILES - 1) {
      STAGE(Amat, bm, k1, 0, nxt);
      asm volatile("s_waitcnt vmcnt(2)" ::: "memory");
    } else {
      asm volatile("s_waitcnt vmcnt(0)" ::: "memory");
    }
    __builtin_amdgcn_s_barrier();
    __builtin_amdgcn_sched_barrier(0);

    bf16x8 bf[4][2];
#pragma unroll
    for (int n = 0; n < 4; n++)
#pragma unroll
      for (int kk = 0; kk < 2; kk++) {
        int r = brow0 + n * 16 + r16;
        bf[n][kk] = *(const bf16x8*)(ldsB + bbase + r * 128 +
                                     (((kk * 4 + g) ^ (r & 7)) * 16));
      }
    {
      bf16x8 a0[2][2];
#pragma unroll
      for (int e = 0; e < 2; e++)
#pragma unroll
        for (int kk = 0; kk < 2; kk++) {
          int r = e * 16 + r16;
          a0[e][kk] = *(const bf16x8*)(ldsB + abase + r * 128 +
                                       (((kk * 4 + g) ^ (r & 7)) * 16));
        }
      asm volatile("s_waitcnt lgkmcnt(0)" ::: "memory");
      __builtin_amdgcn_sched_barrier(0);
      __builtin_amdgcn_s_setprio(1);
#pragma unroll
      for (int e = 0; e < 2; e++)
#pragma unroll
        for (int n = 0; n < 4; n++)
#pragma unroll
          for (int kk = 0; kk < 2; kk++)
            acc[e][n] = __builtin_amdgcn_mfma_f32_16x16x32_bf16(
                a0[e][kk], bf[n][kk], acc[e][n], 0, 0, 0);
      __builtin_amdgcn_s_setprio(0);
    }

    // ---- phases 1..3
#pragma unroll
    for (int p = 1; p < 4; p++) {
      if (t < NTILES - 1) {
        if (p == 1)      STAGE(Amat, bm + 128, k1, 1, nxt);
        else if (p == 2) STAGE(Bmat, bn, k1, 2, nxt);
        else             STAGE(Bmat, bn + 128, k1, 3, nxt);
      }
      bf16x8 ap[2][2];
#pragma unroll
      for (int e = 0; e < 2; e++)
#pragma unroll
        for (int kk = 0; kk < 2; kk++) {
          int r = (2 * p + e) * 16 + r16;
          ap[e][kk] = *(const bf16x8*)(ldsB + abase + r * 128 +
                                       (((kk * 4 + g) ^ (r & 7)) * 16));
        }
      asm volatile("s_waitcnt lgkmcnt(0)" ::: "memory");
      __builtin_amdgcn_sched_barrier(0);
      __builtin_amdgcn_s_setprio(1);
#pragma unroll
      for (int e = 0; e < 2; e++)
#pragma unroll
        for (int n = 0; n < 4; n++)
#pragma unroll
          for (int kk = 0; kk < 2; kk++)
            acc[2 * p + e][n] = __builtin_amdgcn_mfma_f32_16x16x32_bf16(
                ap[e][kk], bf[n][kk], acc[2 * p + e][n], 0, 0, 0);
      __builtin_amdgcn_s_setprio(0);
    }

    __builtin_amdgcn_s_barrier();   // (B): all reads of buf[cur] complete
    __builtin_amdgcn_sched_barrier(0);
    cur = nxt;
  }
#undef STAGE

  if (EPI == 0) {
    const float scale = kv_scale[0];
    const float zp = kv_zp[0];
    const int which = bn >> 10;  // 0=Q 1=K 2=V (uniform per block)
#pragma unroll
    for (int mi = 0; mi < 8; mi++)
#pragma unroll
      for (int ni = 0; ni < 4; ni++)
#pragma unroll
        for (int r = 0; r < 4; r++) {
          int m = bm + wr * 128 + mi * 16 + g * 4 + r;
          int n = bn + wc * 64 + ni * 16 + r16;
          float val = acc[mi][ni][r] + bias[n];
          int hn = n & 1023;
          int bhm = (m >> 11) * 16 + (hn >> 6);
          int tq = m & 2047;
          int d = hn & 63;
          if (which == 0) {
            Qb[((size_t)bhm * TT + tq) * 64 + d] =
                f2bf(val * 0.125f * 1.44269504088896340736f);
          } else {
            float q = rintf(val / scale + zp);   // round-half-even like jnp.round
            q = fminf(fmaxf(q, 0.f), 255.f);
            float deq = (q - zp) * scale;
            if (which == 1) Kb[((size_t)bhm * TT + tq) * 64 + d] = f2bf(deq);
            else            Vt[((size_t)bhm * 64 + d) * TT + tq] = f2bf(deq);
          }
        }
  } else {
#pragma unroll
    for (int mi = 0; mi < 8; mi++)
#pragma unroll
      for (int ni = 0; ni < 4; ni++)
#pragma unroll
        for (int r = 0; r < 4; r++) {
          int m = bm + wr * 128 + mi * 16 + g * 4 + r;
          int n = bn + wc * 64 + ni * 16 + r16;
          Out[(size_t)m * CDIM + n] = acc[mi][ni][r] + bias[n];
        }
  }
}

// ---------------------------------------------------------------------------
// Causal flash attention, swapped-operand 32x32x16 MFMA (guide §B), balanced
// q-block pairing + even/odd KV-tile warp split + 2-phase dbuf pipeline.
__global__ __launch_bounds__(512) void attn_kernel(
    const short* __restrict__ Qb, const short* __restrict__ Kb,
    const short* __restrict__ Vt, short* __restrict__ Caug) {
  __shared__ short Kls[4 * 4096];   // 4 bufs x [64 kv][64 d], 32KB, chunk-swizzled
  __shared__ short Vls[4 * 4096];   // 4 bufs x [64 d][64 kv], 32KB, chunk-swizzled
  const int tid = threadIdx.x;
  const int lane = tid & 63;
  const int w = tid >> 6;
  const int qsub = w & 3;
  const int p = w >> 2;
  const int q32 = lane & 31;
  const int hi = lane >> 5;
  const int bx = blockIdx.x;
  const int bh = blockIdx.y;
  const size_t kvbase = (size_t)bh * TT * 64;
  const int swz = q32 & 7;
  const int b = bh >> 4, h = bh & 15;

  const int srow = tid >> 3;
  const int scg = (tid & 7) ^ (srow & 7);
  const int sdst = w * 1024;

  for (int seg = 0; seg < 2; seg++) {
    const int qb = seg ? bx : 15 - bx;   // pair (15-bx, bx): 34 tiles total
    const int q0 = qb * 128;
    const int q0w = q0 + qsub * 32;
    const int nt = 2 * qb + 2;
    const int ns = nt >> 1;

    bf16x8 qf[4];
    {
      const short* qp = Qb + kvbase + (size_t)(q0w + q32) * 64;
#pragma unroll
      for (int kd = 0; kd < 4; kd++)
        qf[kd] = *(const bf16x8*)(qp + kd * 16 + hi * 8);
    }
    f32x16 accT[2];
#pragma unroll
    for (int i = 0; i < 16; i++) { accT[0][i] = 0.f; accT[1][i] = 0.f; }
    float m_run = -1e30f, l_run = 0.f;

    // prologue: stage pair 0 into buffers {0,1}
#pragma unroll
    for (int t2 = 0; t2 < 2; t2++) {
      int kv0 = t2 * 64;
      gload_lds16(Kb + kvbase + (size_t)(kv0 + srow) * 64 + scg * 8,
                  (char*)Kls + t2 * 8192 + sdst);
      gload_lds16(Vt + kvbase + (size_t)srow * TT + kv0 + scg * 8,
                  (char*)Vls + t2 * 8192 + sdst);
    }
    asm volatile("s_waitcnt vmcnt(0)" ::: "memory");
    __builtin_amdgcn_s_barrier();
    __builtin_amdgcn_sched_barrier(0);

    for (int s = 0; s < ns; s++) {
      if (s + 1 < ns) {
        const int bp = ((s + 1) & 1) * 2;
#pragma unroll
        for (int t2 = 0; t2 < 2; t2++) {
          int kv0 = (2 * (s + 1) + t2) * 64;
          gload_lds16(Kb + kvbase + (size_t)(kv0 + srow) * 64 + scg * 8,
                      (char*)Kls + (bp + t2) * 8192 + sdst);
          gload_lds16(Vt + kvbase + (size_t)srow * TT + kv0 + scg * 8,
                      (char*)Vls + (bp + t2) * 8192 + sdst);
        }
      }
      const int kv0 = (2 * s + p) * 64;
      if (kv0 <= q0w + 31) {   // warp-uniform causal skip
        const char* Kbase = (const char*)Kls + (2 * (s & 1) + p) * 8192;
        const char* Vbase = (const char*)Vls + (2 * (s & 1) + p) * 8192;
        f32x16 sA, sB;
#pragma unroll
        for (int i = 0; i < 16; i++) { sA[i] = 0.f; sB[i] = 0.f; }
        __builtin_amdgcn_s_setprio(1);
#pragma unroll
        for (int kd = 0; kd < 4; kd++) {
          int coff = ((kd * 2 + hi) ^ swz) * 16;
          bf16x8 a0 = *(const bf16x8*)(Kbase + q32 * 128 + coff);
          bf16x8 a1 = *(const bf16x8*)(Kbase + (32 + q32) * 128 + coff);
          sA = __builtin_amdgcn_mfma_f32_32x32x16_bf16(a0, qf[kd], sA, 0, 0, 0);
          sB = __builtin_amdgcn_mfma_f32_32x32x16_bf16(a1, qf[kd], sB, 0, 0, 0);
        }
        __builtin_amdgcn_s_setprio(0);
        const int qg = q0w + q32;
        if (kv0 + 63 > q0w) {
#pragma unroll
          for (int r = 0; r < 16; r++) {
            int kvr = kv0 + (r & 3) + 8 * (r >> 2) + 4 * hi;
            if (kvr > qg) sA[r] = -1e30f;
            if (kvr + 32 > qg) sB[r] = -1e30f;
          }
        }
        float mx = sA[0];
#pragma unroll
        for (int r = 1; r < 16; r++) mx = fmaxf(mx, sA[r]);
#pragma unroll
        for (int r = 0; r < 16; r++) mx = fmaxf(mx, sB[r]);
        mx = fmaxf(mx, __shfl_xor(mx, 32));
        float mnew = fmaxf(m_run, mx);
        float corr = exp2f(m_run - mnew);
        float rs = 0.f;
#pragma unroll
        for (int r = 0; r < 16; r++) {
          sA[r] = exp2f(sA[r] - mnew);
          sB[r] = exp2f(sB[r] - mnew);
          rs += sA[r] + sB[r];
        }
        rs += __shfl_xor(rs, 32);
        l_run = l_run * corr + rs;
        m_run = mnew;
#pragma unroll
        for (int r = 0; r < 16; r++) { accT[0][r] *= corr; accT[1][r] *= corr; }

        bf16x8 pf[4];
#pragma unroll
        for (int t2 = 0; t2 < 2; t2++) {
#pragma unroll
          for (int s01 = 0; s01 < 2; s01++) {
            int base = 8 * s01;
            unsigned int wlo0, wlo1, whi0, whi1;
            if (t2 == 0) {
              wlo0 = cvt_pk_bf16(sA[base + 0], sA[base + 1]);
              wlo1 = cvt_pk_bf16(sA[base + 2], sA[base + 3]);
              whi0 = cvt_pk_bf16(sA[base + 4], sA[base + 5]);
              whi1 = cvt_pk_bf16(sA[base + 6], sA[base + 7]);
            } else {
              wlo0 = cvt_pk_bf16(sB[base + 0], sB[base + 1]);
              wlo1 = cvt_pk_bf16(sB[base + 2], sB[base + 3]);
              whi0 = cvt_pk_bf16(sB[base + 4], sB[base + 5]);
              whi1 = cvt_pk_bf16(sB[base + 6], sB[base + 7]);
            }
            asm volatile("v_permlane32_swap_b32 %0, %1" : "+v"(wlo0), "+v"(whi0));
            asm volatile("v_permlane32_swap_b32 %0, %1" : "+v"(wlo1), "+v"(whi1));
            union { unsigned int u[4]; bf16x8 v; } cc;
            cc.u[0] = wlo0; cc.u[1] = wlo1; cc.u[2] = whi0; cc.u[3] = whi1;
            pf[t2 * 2 + s01] = cc.v;
          }
        }
        __builtin_amdgcn_s_setprio(1);
#pragma unroll
        for (int db = 0; db < 2; db++) {
          const int row = db * 32 + q32;
#pragma unroll
          for (int ks = 0; ks < 4; ks++) {
            bf16x8 vf = *(const bf16x8*)(Vbase + row * 128 +
                                         (((ks * 2 + hi) ^ swz) * 16));
            accT[db] = __builtin_amdgcn_mfma_f32_32x32x16_bf16(vf, pf[ks],
                                                               accT[db], 0, 0, 0);
          }
        }
        __builtin_amdgcn_s_setprio(0);
      }
      asm volatile("s_waitcnt vmcnt(0) lgkmcnt(0)" ::: "memory");
      __builtin_amdgcn_s_barrier();
      __builtin_amdgcn_sched_barrier(0);
    }

    // merge parity partials through LDS (reuse K/V buffers as scratch)
    float* scrO = (float*)Kls;
    float* scrML = (float*)Vls;
    if (p == 1) {
#pragma unroll
      for (int db = 0; db < 2; db++)
#pragma unroll
        for (int r = 0; r < 16; r++)
          scrO[qsub * 2048 + (db * 16 + r) * 64 + lane] = accT[db][r];
      scrML[qsub * 64 + lane] = m_run;
      scrML[256 + qsub * 64 + lane] = l_run;
    }
    __syncthreads();
    if (p == 0) {
      float m_o = scrML[qsub * 64 + lane];
      float l_o = scrML[256 + qsub * 64 + lane];
      float mm = fmaxf(m_run, m_o);
      float ce = exp2f(m_run - mm), co = exp2f(m_o - mm);
      float lt = l_run * ce + l_o * co;
      float rinv = 1.f / lt;
      short* cp = Caug + (size_t)(b * TT + q0w + q32) * KAUG + h * 64;
#pragma unroll
      for (int db = 0; db < 2; db++)
#pragma unroll
        for (int rg = 0; rg < 4; rg++) {
          short4v pk4;
#pragma unroll
          for (int rr = 0; rr < 4; rr++) {
            int r = rg * 4 + rr;
            float v = accT[db][r] * ce +
                      scrO[qsub * 2048 + (db * 16 + r) * 64 + lane] * co;
            pk4[rr] = f2bf(v * rinv);
          }
          *(short4v*)(cp + db * 32 + rg * 8 + hi * 4) = pk4;
        }
    }
    __syncthreads();
  }
}

// ---------------------------------------------------------------------------
extern "C" void kernel_launch(void* const* d_in, const int* in_sizes, int n_in,
                              void* d_out, int out_size, void* d_ws, size_t ws_size,
                              hipStream_t stream) {
  const float* x       = (const float*)d_in[0];
  const float* W_attn  = (const float*)d_in[1];
  const float* b_attn  = (const float*)d_in[2];
  const float* A_attn  = (const float*)d_in[3];
  const float* B_attn  = (const float*)d_in[4];
  const float* W_proj  = (const float*)d_in[5];
  const float* b_proj  = (const float*)d_in[6];
  const float* A_proj  = (const float*)d_in[7];
  const float* B_proj  = (const float*)d_in[8];
  const float* kv_scale = (const float*)d_in[9];
  const float* kv_zp    = (const float*)d_in[10];
  float* out = (float*)d_out;

  char* p = (char*)d_ws;
  short* Xaug  = (short*)p; p += (size_t)BT * KAUG * 2;
  short* Waug1 = (short*)p; p += (size_t)3072 * KAUG * 2;
  short* Waug2 = (short*)p; p += (size_t)1024 * KAUG * 2;
  short* Caug  = (short*)p; p += (size_t)BT * KAUG * 2;
  short* Qb    = (short*)p; p += (size_t)32 * TT * 64 * 2;
  short* Kb    = (short*)p; p += (size_t)32 * TT * 64 * 2;
  short* Vt    = (short*)p; p += (size_t)32 * TT * 64 * 2;

  rank1_kernel<<<dim3(256), dim3(256), 0, stream>>>(x, A_attn, Xaug);
  packw_kernel<<<dim3(1632), dim3(256), 0, stream>>>(W_attn, B_attn, Waug1, 3072);
  packw_kernel<<<dim3(544), dim3(256), 0, stream>>>(W_proj, B_proj, Waug2, 1024);
  gemm256_kernel<0><<<dim3(192), dim3(512), 0, stream>>>(
      Xaug, Waug1, b_attn, kv_scale, kv_zp, Qb, Kb, Vt, (float*)nullptr);
  attn_kernel<<<dim3(8, 32), dim3(512), 0, stream>>>(Qb, Kb, Vt, Caug);
  rank2_kernel<<<dim3(256), dim3(256), 0, stream>>>(A_proj, Caug);
  gemm256_kernel<1><<<dim3(64), dim3(512), 0, stream>>>(
      Caug, Waug2, b_proj, kv_scale, kv_zp,
      (short*)nullptr, (short*)nullptr, (short*)nullptr, out);
}

// Round 6
// 195.435 us; speedup vs baseline: 1.0697x; 1.0697x over previous
//
#include <hip/hip_runtime.h>
#include <math.h>

#define TT 2048
#define CDIM 1024
#define KAUG 1088
#define BT 4096
#define NTILES 17   // KAUG / 64

typedef __attribute__((ext_vector_type(8))) short bf16x8;
typedef __attribute__((ext_vector_type(4))) short short4v;
typedef __attribute__((ext_vector_type(4))) float f32x4;
typedef __attribute__((ext_vector_type(16))) float f32x16;

static __device__ __forceinline__ float bf2f(short s) {
  union { unsigned int u; float f; } c;
  c.u = ((unsigned int)(unsigned short)s) << 16;
  return c.f;
}
static __device__ __forceinline__ short f2bf(float f) {
  union { float f; unsigned int u; } c; c.f = f;
  unsigned int u = c.u;
  u += 0x7fff + ((u >> 16) & 1);   // round-to-nearest-even
  return (short)(u >> 16);
}

static __device__ __forceinline__ void gload_lds16(const void* g, void* l) {
  __builtin_amdgcn_global_load_lds(
      (const __attribute__((address_space(1))) void*)g,
      (__attribute__((address_space(3))) void*)l, 16, 0, 0);
}

static __device__ __forceinline__ unsigned int cvt_pk_bf16(float lo, float hi) {
  unsigned int r;
  asm("v_cvt_pk_bf16_f32 %0, %1, %2" : "=v"(r) : "v"(lo), "v"(hi));
  return r;
}

// ---------------------------------------------------------------------------
// rank1: xa = x @ A_attn^T (fp32), fused with packing x -> Xaug (bf16) and
// writing cols [1024,1040) = 2*xa (bf16), [1040,1088) = 0.
__global__ __launch_bounds__(256) void rank1_kernel(
    const float* __restrict__ x, const float* __restrict__ Aattn,
    short* __restrict__ Xaug) {
  __shared__ float xls[16][1024];
  const int tid = threadIdx.x;
  const int row0 = blockIdx.x * 16;
  for (int i = tid; i < 16 * 256; i += 256) {
    int row = i >> 8, c4 = (i & 255) * 4;
    float4 v = *(const float4*)(x + (size_t)(row0 + row) * CDIM + c4);
    *(float4*)&xls[row][c4] = v;
    short4v p;
    p.x = f2bf(v.x); p.y = f2bf(v.y); p.z = f2bf(v.z); p.w = f2bf(v.w);
    *(short4v*)(Xaug + (size_t)(row0 + row) * KAUG + c4) = p;
  }
  __syncthreads();
  const int row = tid >> 4, r = tid & 15;
  float acc = 0.f;
  for (int c = 0; c < 1024; c += 4) {
    float4 a = *(const float4*)(Aattn + (size_t)r * 1024 + c);
    float4 xv = *(const float4*)&xls[row][c];
    acc += a.x * xv.x + a.y * xv.y + a.z * xv.z + a.w * xv.w;
  }
  Xaug[(size_t)(row0 + row) * KAUG + 1024 + r] = f2bf(2.f * acc);
  for (int i = tid; i < 16 * 48; i += 256) {
    int rr = i / 48, cc = 1040 + (i % 48);
    Xaug[(size_t)(row0 + rr) * KAUG + cc] = 0;
  }
}

// ---------------------------------------------------------------------------
// rank2: ca = ctx @ A_proj^T, ctx = Caug cols [0,1024) (bf16, stride KAUG);
// writes Caug cols [1024,1040) = 2*ca (bf16), [1040,1088) = 0.
__global__ __launch_bounds__(256) void rank2_kernel(
    const float* __restrict__ Aproj, short* __restrict__ Caug) {
  __shared__ float cls[16][1024];
  const int tid = threadIdx.x;
  const int row0 = blockIdx.x * 16;
  for (int i = tid; i < 16 * 128; i += 256) {
    int row = i >> 7, c8 = (i & 127) * 8;
    bf16x8 v = *(const bf16x8*)(Caug + (size_t)(row0 + row) * KAUG + c8);
#pragma unroll
    for (int j = 0; j < 8; j++) cls[row][c8 + j] = bf2f(v[j]);
  }
  __syncthreads();
  const int row = tid >> 4, r = tid & 15;
  float acc = 0.f;
  for (int c = 0; c < 1024; c += 4) {
    float4 a = *(const float4*)(Aproj + (size_t)r * 1024 + c);
    float4 xv = *(const float4*)&cls[row][c];
    acc += a.x * xv.x + a.y * xv.y + a.z * xv.z + a.w * xv.w;
  }
  Caug[(size_t)(row0 + row) * KAUG + 1024 + r] = f2bf(2.f * acc);
  for (int i = tid; i < 16 * 48; i += 256) {
    int rr = i / 48, cc = 1040 + (i % 48);
    Caug[(size_t)(row0 + rr) * KAUG + cc] = 0;
  }
}

// ---------------------------------------------------------------------------
// pack W (fp32 [rows][1024]) + Bmat (fp32 [rows][16]) -> Waug bf16 [rows][1088]
__global__ __launch_bounds__(256) void packw_kernel(
    const float* __restrict__ W, const float* __restrict__ Bm,
    short* __restrict__ Waug, int rows) {
  int i = blockIdx.x * 256 + threadIdx.x;
  int total = rows * 136;
  if (i >= total) return;
  int row = i / 136;
  int c8 = (i - row * 136) * 8;
  bf16x8 p;
  if (c8 < 1024) {
    float4 v0 = *(const float4*)(W + (size_t)row * 1024 + c8);
    float4 v1 = *(const float4*)(W + (size_t)row * 1024 + c8 + 4);
    p[0] = f2bf(v0.x); p[1] = f2bf(v0.y); p[2] = f2bf(v0.z); p[3] = f2bf(v0.w);
    p[4] = f2bf(v1.x); p[5] = f2bf(v1.y); p[6] = f2bf(v1.z); p[7] = f2bf(v1.w);
  } else if (c8 < 1040) {
#pragma unroll
    for (int j = 0; j < 8; j++) p[j] = f2bf(Bm[(size_t)row * 16 + (c8 - 1024) + j]);
  } else {
#pragma unroll
    for (int j = 0; j < 8; j++) p[j] = 0;
  }
  *(bf16x8*)(Waug + (size_t)row * KAUG + c8) = p;
}

// ---------------------------------------------------------------------------
// 128x128 bf16 MFMA GEMM, K = KAUG, 2-phase double-buffered (T3 minimum
// recipe): per tile issue STAGE(t+1) into buf^1 FIRST, then ds_read+MFMA on
// buf[cur], then ONE vmcnt(0)+barrier at tile end — loads are waited a full
// compute-phase after issue. Buffer stride 32 KB (A@0, B@+16K); 64 KB LDS
// total -> 2 blocks/CU co-resident.
// Grid is 1-D, bijective XCD swizzle; bm = (sw&31)*128, bn = (sw>>5)*128.
// EPI 0: QKV epilogue; EPI 1: proj epilogue (bias, fp32 out)
template <int EPI>
__global__ __launch_bounds__(256) void gemm_kernel(
    const short* __restrict__ Amat, const short* __restrict__ Bmat,
    const float* __restrict__ bias,
    const float* __restrict__ kv_scale, const float* __restrict__ kv_zp,
    short* __restrict__ Qb, short* __restrict__ Kb, short* __restrict__ Vt,
    float* __restrict__ Out) {
  __shared__ short lds[2 * 2 * 128 * 64];   // [buf][A/B][128*64] = 64 KB
  char* const ldsB = (char*)lds;
  const int tid = threadIdx.x;
  const int lane = tid & 63;
  const int wid = tid >> 6;
  const int wr = wid >> 1, wc = wid & 1;
  const int r16 = lane & 15, g = lane >> 4;

  // bijective XCD swizzle (gridDim.x % 8 == 0: 768 or 256)
  const int nwg = gridDim.x;
  const int sw = (blockIdx.x & 7) * (nwg >> 3) + (blockIdx.x >> 3);
  const int bm = (sw & 31) * 128;
  const int bn = (sw >> 5) * 128;

  // stage one K-tile (A+B) into buffer `buf`; LDS chunk (row,cs) holds
  // global chunk (row, cs^(row&7)); dest byte = chunkIndex*16 (linear).
  // Buffer stride 32768 B: A at +0, B at +16384.
#define STAGE_TILE(buf, k0)                                                   \
  do {                                                                        \
    _Pragma("unroll") for (int i = 0; i < 4; i++) {                           \
      int L = i * 256 + tid;                                                  \
      int row = L >> 3;                                                       \
      int cg = (L & 7) ^ (row & 7);                                           \
      char* d = ldsB + (buf) * 32768 + (i * 256 + wid * 64) * 16;             \
      gload_lds16(Amat + (size_t)(bm + row) * KAUG + (k0) + cg * 8, d);       \
      gload_lds16(Bmat + (size_t)(bn + row) * KAUG + (k0) + cg * 8,           \
                  d + 16384);                                                 \
    }                                                                         \
  } while (0)

  f32x4 zero = {0.f, 0.f, 0.f, 0.f};
  f32x4 acc[4][4];
#pragma unroll
  for (int i = 0; i < 4; i++)
#pragma unroll
    for (int j = 0; j < 4; j++) acc[i][j] = zero;

  STAGE_TILE(0, 0);
  asm volatile("s_waitcnt vmcnt(0)" ::: "memory");
  __builtin_amdgcn_s_barrier();
  __builtin_amdgcn_sched_barrier(0);

  int cur = 0;
  for (int t = 0; t < NTILES; ++t) {
    if (t + 1 < NTILES) STAGE_TILE(cur ^ 1, (t + 1) * 64);
    __builtin_amdgcn_sched_barrier(0);   // keep prefetch issue ahead of reads
    const char* Ab = ldsB + cur * 32768;
    const char* Bb = Ab + 16384;
#pragma unroll
    for (int kk = 0; kk < 2; kk++) {
      bf16x8 a[4], b[4];
#pragma unroll
      for (int mi = 0; mi < 4; mi++) {
        int row = wr * 64 + mi * 16 + r16;
        int cs = (kk * 4 + g) ^ (row & 7);
        a[mi] = *(const bf16x8*)(Ab + (row * 8 + cs) * 16);
      }
#pragma unroll
      for (int ni = 0; ni < 4; ni++) {
        int row = wc * 64 + ni * 16 + r16;
        int cs = (kk * 4 + g) ^ (row & 7);
        b[ni] = *(const bf16x8*)(Bb + (row * 8 + cs) * 16);
      }
      __builtin_amdgcn_s_setprio(1);
#pragma unroll
      for (int mi = 0; mi < 4; mi++)
#pragma unroll
        for (int ni = 0; ni < 4; ni++)
          acc[mi][ni] = __builtin_amdgcn_mfma_f32_16x16x32_bf16(
              a[mi], b[ni], acc[mi][ni], 0, 0, 0);
      __builtin_amdgcn_s_setprio(0);
    }
    asm volatile("s_waitcnt vmcnt(0)" ::: "memory");
    __builtin_amdgcn_s_barrier();
    __builtin_amdgcn_sched_barrier(0);
    cur ^= 1;
  }
#undef STAGE_TILE

  if (EPI == 0) {
    const float scale = kv_scale[0];
    const float zp = kv_zp[0];
    const int which = bn >> 10;  // 0=Q 1=K 2=V (uniform per block)
#pragma unroll
    for (int mi = 0; mi < 4; mi++)
#pragma unroll
      for (int ni = 0; ni < 4; ni++)
#pragma unroll
        for (int r = 0; r < 4; r++) {
          int m = bm + wr * 64 + mi * 16 + g * 4 + r;
          int n = bn + wc * 64 + ni * 16 + r16;
          float val = acc[mi][ni][r] + bias[n];
          int hn = n & 1023;
          int bhm = (m >> 11) * 16 + (hn >> 6);
          int tq = m & 2047;
          int d = hn & 63;
          if (which == 0) {
            Qb[((size_t)bhm * TT + tq) * 64 + d] =
                f2bf(val * 0.125f * 1.44269504088896340736f);
          } else {
            float q = rintf(val / scale + zp);   // round-half-even like jnp.round
            q = fminf(fmaxf(q, 0.f), 255.f);
            float deq = (q - zp) * scale;
            if (which == 1) Kb[((size_t)bhm * TT + tq) * 64 + d] = f2bf(deq);
            else            Vt[((size_t)bhm * 64 + d) * TT + tq] = f2bf(deq);
          }
        }
  } else {
#pragma unroll
    for (int mi = 0; mi < 4; mi++)
#pragma unroll
      for (int ni = 0; ni < 4; ni++)
#pragma unroll
        for (int r = 0; r < 4; r++) {
          int m = bm + wr * 64 + mi * 16 + g * 4 + r;
          int n = bn + wc * 64 + ni * 16 + r16;
          Out[(size_t)m * CDIM + n] = acc[mi][ni][r] + bias[n];
        }
  }
}

// ---------------------------------------------------------------------------
// Causal flash attention, swapped-operand 32x32x16 MFMA (guide §B), balanced
// q-block pairing + even/odd KV-tile warp split + 2-phase dbuf pipeline.
__global__ __launch_bounds__(512) void attn_kernel(
    const short* __restrict__ Qb, const short* __restrict__ Kb,
    const short* __restrict__ Vt, short* __restrict__ Caug) {
  __shared__ short Kls[4 * 4096];   // 4 bufs x [64 kv][64 d], 32KB, chunk-swizzled
  __shared__ short Vls[4 * 4096];   // 4 bufs x [64 d][64 kv], 32KB, chunk-swizzled
  const int tid = threadIdx.x;
  const int lane = tid & 63;
  const int w = tid >> 6;
  const int qsub = w & 3;
  const int p = w >> 2;
  const int q32 = lane & 31;
  const int hi = lane >> 5;
  const int bx = blockIdx.x;
  const int bh = blockIdx.y;
  const size_t kvbase = (size_t)bh * TT * 64;
  const int swz = q32 & 7;
  const int b = bh >> 4, h = bh & 15;

  const int srow = tid >> 3;
  const int scg = (tid & 7) ^ (srow & 7);
  const int sdst = w * 1024;

  for (int seg = 0; seg < 2; seg++) {
    const int qb = seg ? bx : 15 - bx;   // pair (15-bx, bx): 34 tiles total
    const int q0 = qb * 128;
    const int q0w = q0 + qsub * 32;
    const int nt = 2 * qb + 2;
    const int ns = nt >> 1;

    bf16x8 qf[4];
    {
      const short* qp = Qb + kvbase + (size_t)(q0w + q32) * 64;
#pragma unroll
      for (int kd = 0; kd < 4; kd++)
        qf[kd] = *(const bf16x8*)(qp + kd * 16 + hi * 8);
    }
    f32x16 accT[2];
#pragma unroll
    for (int i = 0; i < 16; i++) { accT[0][i] = 0.f; accT[1][i] = 0.f; }
    float m_run = -1e30f, l_run = 0.f;

    // prologue: stage pair 0 into buffers {0,1}
#pragma unroll
    for (int t2 = 0; t2 < 2; t2++) {
      int kv0 = t2 * 64;
      gload_lds16(Kb + kvbase + (size_t)(kv0 + srow) * 64 + scg * 8,
                  (char*)Kls + t2 * 8192 + sdst);
      gload_lds16(Vt + kvbase + (size_t)srow * TT + kv0 + scg * 8,
                  (char*)Vls + t2 * 8192 + sdst);
    }
    asm volatile("s_waitcnt vmcnt(0)" ::: "memory");
    __builtin_amdgcn_s_barrier();
    __builtin_amdgcn_sched_barrier(0);

    for (int s = 0; s < ns; s++) {
      if (s + 1 < ns) {
        const int bp = ((s + 1) & 1) * 2;
#pragma unroll
        for (int t2 = 0; t2 < 2; t2++) {
          int kv0 = (2 * (s + 1) + t2) * 64;
          gload_lds16(Kb + kvbase + (size_t)(kv0 + srow) * 64 + scg * 8,
                      (char*)Kls + (bp + t2) * 8192 + sdst);
          gload_lds16(Vt + kvbase + (size_t)srow * TT + kv0 + scg * 8,
                      (char*)Vls + (bp + t2) * 8192 + sdst);
        }
      }
      const int kv0 = (2 * s + p) * 64;
      if (kv0 <= q0w + 31) {   // warp-uniform causal skip
        const char* Kbase = (const char*)Kls + (2 * (s & 1) + p) * 8192;
        const char* Vbase = (const char*)Vls + (2 * (s & 1) + p) * 8192;
        f32x16 sA, sB;
#pragma unroll
        for (int i = 0; i < 16; i++) { sA[i] = 0.f; sB[i] = 0.f; }
        __builtin_amdgcn_s_setprio(1);
#pragma unroll
        for (int kd = 0; kd < 4; kd++) {
          int coff = ((kd * 2 + hi) ^ swz) * 16;
          bf16x8 a0 = *(const bf16x8*)(Kbase + q32 * 128 + coff);
          bf16x8 a1 = *(const bf16x8*)(Kbase + (32 + q32) * 128 + coff);
          sA = __builtin_amdgcn_mfma_f32_32x32x16_bf16(a0, qf[kd], sA, 0, 0, 0);
          sB = __builtin_amdgcn_mfma_f32_32x32x16_bf16(a1, qf[kd], sB, 0, 0, 0);
        }
        __builtin_amdgcn_s_setprio(0);
        const int qg = q0w + q32;
        if (kv0 + 63 > q0w) {
#pragma unroll
          for (int r = 0; r < 16; r++) {
            int kvr = kv0 + (r & 3) + 8 * (r >> 2) + 4 * hi;
            if (kvr > qg) sA[r] = -1e30f;
            if (kvr + 32 > qg) sB[r] = -1e30f;
          }
        }
        float mx = sA[0];
#pragma unroll
        for (int r = 1; r < 16; r++) mx = fmaxf(mx, sA[r]);
#pragma unroll
        for (int r = 0; r < 16; r++) mx = fmaxf(mx, sB[r]);
        mx = fmaxf(mx, __shfl_xor(mx, 32));
        float mnew = fmaxf(m_run, mx);
        float corr = exp2f(m_run - mnew);
        float rs = 0.f;
#pragma unroll
        for (int r = 0; r < 16; r++) {
          sA[r] = exp2f(sA[r] - mnew);
          sB[r] = exp2f(sB[r] - mnew);
          rs += sA[r] + sB[r];
        }
        rs += __shfl_xor(rs, 32);
        l_run = l_run * corr + rs;
        m_run = mnew;
#pragma unroll
        for (int r = 0; r < 16; r++) { accT[0][r] *= corr; accT[1][r] *= corr; }

        bf16x8 pf[4];
#pragma unroll
        for (int t2 = 0; t2 < 2; t2++) {
#pragma unroll
          for (int s01 = 0; s01 < 2; s01++) {
            int base = 8 * s01;
            unsigned int wlo0, wlo1, whi0, whi1;
            if (t2 == 0) {
              wlo0 = cvt_pk_bf16(sA[base + 0], sA[base + 1]);
              wlo1 = cvt_pk_bf16(sA[base + 2], sA[base + 3]);
              whi0 = cvt_pk_bf16(sA[base + 4], sA[base + 5]);
              whi1 = cvt_pk_bf16(sA[base + 6], sA[base + 7]);
            } else {
              wlo0 = cvt_pk_bf16(sB[base + 0], sB[base + 1]);
              wlo1 = cvt_pk_bf16(sB[base + 2], sB[base + 3]);
              whi0 = cvt_pk_bf16(sB[base + 4], sB[base + 5]);
              whi1 = cvt_pk_bf16(sB[base + 6], sB[base + 7]);
            }
            asm volatile("v_permlane32_swap_b32 %0, %1" : "+v"(wlo0), "+v"(whi0));
            asm volatile("v_permlane32_swap_b32 %0, %1" : "+v"(wlo1), "+v"(whi1));
            union { unsigned int u[4]; bf16x8 v; } cc;
            cc.u[0] = wlo0; cc.u[1] = wlo1; cc.u[2] = whi0; cc.u[3] = whi1;
            pf[t2 * 2 + s01] = cc.v;
          }
        }
        __builtin_amdgcn_s_setprio(1);
#pragma unroll
        for (int db = 0; db < 2; db++) {
          const int row = db * 32 + q32;
#pragma unroll
          for (int ks = 0; ks < 4; ks++) {
            bf16x8 vf = *(const bf16x8*)(Vbase + row * 128 +
                                         (((ks * 2 + hi) ^ swz) * 16));
            accT[db] = __builtin_amdgcn_mfma_f32_32x32x16_bf16(vf, pf[ks],
                                                               accT[db], 0, 0, 0);
          }
        }
        __builtin_amdgcn_s_setprio(0);
      }
      asm volatile("s_waitcnt vmcnt(0) lgkmcnt(0)" ::: "memory");
      __builtin_amdgcn_s_barrier();
      __builtin_amdgcn_sched_barrier(0);
    }

    // merge parity partials through LDS (reuse K/V buffers as scratch)
    float* scrO = (float*)Kls;
    float* scrML = (float*)Vls;
    if (p == 1) {
#pragma unroll
      for (int db = 0; db < 2; db++)
#pragma unroll
        for (int r = 0; r < 16; r++)
          scrO[qsub * 2048 + (db * 16 + r) * 64 + lane] = accT[db][r];
      scrML[qsub * 64 + lane] = m_run;
      scrML[256 + qsub * 64 + lane] = l_run;
    }
    __syncthreads();
    if (p == 0) {
      float m_o = scrML[qsub * 64 + lane];
      float l_o = scrML[256 + qsub * 64 + lane];
      float mm = fmaxf(m_run, m_o);
      float ce = exp2f(m_run - mm), co = exp2f(m_o - mm);
      float lt = l_run * ce + l_o * co;
      float rinv = 1.f / lt;
      short* cp = Caug + (size_t)(b * TT + q0w + q32) * KAUG + h * 64;
#pragma unroll
      for (int db = 0; db < 2; db++)
#pragma unroll
        for (int rg = 0; rg < 4; rg++) {
          short4v pk4;
#pragma unroll
          for (int rr = 0; rr < 4; rr++) {
            int r = rg * 4 + rr;
            float v = accT[db][r] * ce +
                      scrO[qsub * 2048 + (db * 16 + r) * 64 + lane] * co;
            pk4[rr] = f2bf(v * rinv);
          }
          *(short4v*)(cp + db * 32 + rg * 8 + hi * 4) = pk4;
        }
    }
    __syncthreads();
  }
}

// ---------------------------------------------------------------------------
extern "C" void kernel_launch(void* const* d_in, const int* in_sizes, int n_in,
                              void* d_out, int out_size, void* d_ws, size_t ws_size,
                              hipStream_t stream) {
  const float* x       = (const float*)d_in[0];
  const float* W_attn  = (const float*)d_in[1];
  const float* b_attn  = (const float*)d_in[2];
  const float* A_attn  = (const float*)d_in[3];
  const float* B_attn  = (const float*)d_in[4];
  const float* W_proj  = (const float*)d_in[5];
  const float* b_proj  = (const float*)d_in[6];
  const float* A_proj  = (const float*)d_in[7];
  const float* B_proj  = (const float*)d_in[8];
  const float* kv_scale = (const float*)d_in[9];
  const float* kv_zp    = (const float*)d_in[10];
  float* out = (float*)d_out;

  char* p = (char*)d_ws;
  short* Xaug  = (short*)p; p += (size_t)BT * KAUG * 2;
  short* Waug1 = (short*)p; p += (size_t)3072 * KAUG * 2;
  short* Waug2 = (short*)p; p += (size_t)1024 * KAUG * 2;
  short* Caug  = (short*)p; p += (size_t)BT * KAUG * 2;
  short* Qb    = (short*)p; p += (size_t)32 * TT * 64 * 2;
  short* Kb    = (short*)p; p += (size_t)32 * TT * 64 * 2;
  short* Vt    = (short*)p; p += (size_t)32 * TT * 64 * 2;

  rank1_kernel<<<dim3(256), dim3(256), 0, stream>>>(x, A_attn, Xaug);
  packw_kernel<<<dim3(1632), dim3(256), 0, stream>>>(W_attn, B_attn, Waug1, 3072);
  packw_kernel<<<dim3(544), dim3(256), 0, stream>>>(W_proj, B_proj, Waug2, 1024);
  gemm_kernel<0><<<dim3(768), dim3(256), 0, stream>>>(
      Xaug, Waug1, b_attn, kv_scale, kv_zp, Qb, Kb, Vt, (float*)nullptr);
  attn_kernel<<<dim3(8, 32), dim3(512), 0, stream>>>(Qb, Kb, Vt, Caug);
  rank2_kernel<<<dim3(256), dim3(256), 0, stream>>>(A_proj, Caug);
  gemm_kernel<1><<<dim3(256), dim3(256), 0, stream>>>(
      Caug, Waug2, b_proj, kv_scale, kv_zp,
      (short*)nullptr, (short*)nullptr, (short*)nullptr, out);
}

// Round 7
// 182.521 us; speedup vs baseline: 1.1454x; 1.0708x over previous
//
#include <hip/hip_runtime.h>
#include <math.h>

#define TT 2048
#define CDIM 1024
#define KAUG 1088
#define BT 4096
#define NTILES 17   // KAUG / 64

typedef __attribute__((ext_vector_type(8))) short bf16x8;
typedef __attribute__((ext_vector_type(4))) short short4v;
typedef __attribute__((ext_vector_type(4))) float f32x4;
typedef __attribute__((ext_vector_type(16))) float f32x16;

static __device__ __forceinline__ float bf2f(short s) {
  union { unsigned int u; float f; } c;
  c.u = ((unsigned int)(unsigned short)s) << 16;
  return c.f;
}
static __device__ __forceinline__ short f2bf(float f) {
  union { float f; unsigned int u; } c; c.f = f;
  unsigned int u = c.u;
  u += 0x7fff + ((u >> 16) & 1);   // round-to-nearest-even
  return (short)(u >> 16);
}

static __device__ __forceinline__ void gload_lds16(const void* g, void* l) {
  __builtin_amdgcn_global_load_lds(
      (const __attribute__((address_space(1))) void*)g,
      (__attribute__((address_space(3))) void*)l, 16, 0, 0);
}

static __device__ __forceinline__ unsigned int cvt_pk_bf16(float lo, float hi) {
  unsigned int r;
  asm("v_cvt_pk_bf16_f32 %0, %1, %2" : "=v"(r) : "v"(lo), "v"(hi));
  return r;
}

// ---------------------------------------------------------------------------
// rank1: xa = x @ A_attn^T (fp32), fused with packing x -> Xaug (bf16) and
// writing cols [1024,1040) = 2*xa (bf16), [1040,1088) = 0.
__global__ __launch_bounds__(256) void rank1_kernel(
    const float* __restrict__ x, const float* __restrict__ Aattn,
    short* __restrict__ Xaug) {
  __shared__ float xls[16][1024];
  const int tid = threadIdx.x;
  const int row0 = blockIdx.x * 16;
  for (int i = tid; i < 16 * 256; i += 256) {
    int row = i >> 8, c4 = (i & 255) * 4;
    float4 v = *(const float4*)(x + (size_t)(row0 + row) * CDIM + c4);
    *(float4*)&xls[row][c4] = v;
    short4v p;
    p.x = f2bf(v.x); p.y = f2bf(v.y); p.z = f2bf(v.z); p.w = f2bf(v.w);
    *(short4v*)(Xaug + (size_t)(row0 + row) * KAUG + c4) = p;
  }
  __syncthreads();
  const int row = tid >> 4, r = tid & 15;
  float acc = 0.f;
  for (int c = 0; c < 1024; c += 4) {
    float4 a = *(const float4*)(Aattn + (size_t)r * 1024 + c);
    float4 xv = *(const float4*)&xls[row][c];
    acc += a.x * xv.x + a.y * xv.y + a.z * xv.z + a.w * xv.w;
  }
  Xaug[(size_t)(row0 + row) * KAUG + 1024 + r] = f2bf(2.f * acc);
  for (int i = tid; i < 16 * 48; i += 256) {
    int rr = i / 48, cc = 1040 + (i % 48);
    Xaug[(size_t)(row0 + rr) * KAUG + cc] = 0;
  }
}

// ---------------------------------------------------------------------------
// rank2: ca = ctx @ A_proj^T, ctx = Caug cols [0,1024) (bf16, stride KAUG);
// writes Caug cols [1024,1040) = 2*ca (bf16), [1040,1088) = 0.
__global__ __launch_bounds__(256) void rank2_kernel(
    const float* __restrict__ Aproj, short* __restrict__ Caug) {
  __shared__ float cls[16][1024];
  const int tid = threadIdx.x;
  const int row0 = blockIdx.x * 16;
  for (int i = tid; i < 16 * 128; i += 256) {
    int row = i >> 7, c8 = (i & 127) * 8;
    bf16x8 v = *(const bf16x8*)(Caug + (size_t)(row0 + row) * KAUG + c8);
#pragma unroll
    for (int j = 0; j < 8; j++) cls[row][c8 + j] = bf2f(v[j]);
  }
  __syncthreads();
  const int row = tid >> 4, r = tid & 15;
  float acc = 0.f;
  for (int c = 0; c < 1024; c += 4) {
    float4 a = *(const float4*)(Aproj + (size_t)r * 1024 + c);
    float4 xv = *(const float4*)&cls[row][c];
    acc += a.x * xv.x + a.y * xv.y + a.z * xv.z + a.w * xv.w;
  }
  Caug[(size_t)(row0 + row) * KAUG + 1024 + r] = f2bf(2.f * acc);
  for (int i = tid; i < 16 * 48; i += 256) {
    int rr = i / 48, cc = 1040 + (i % 48);
    Caug[(size_t)(row0 + rr) * KAUG + cc] = 0;
  }
}

// ---------------------------------------------------------------------------
// pack W (fp32 [rows][1024]) + Bmat (fp32 [rows][16]) -> Waug bf16 [rows][1088]
__global__ __launch_bounds__(256) void packw_kernel(
    const float* __restrict__ W, const float* __restrict__ Bm,
    short* __restrict__ Waug, int rows) {
  int i = blockIdx.x * 256 + threadIdx.x;
  int total = rows * 136;
  if (i >= total) return;
  int row = i / 136;
  int c8 = (i - row * 136) * 8;
  bf16x8 p;
  if (c8 < 1024) {
    float4 v0 = *(const float4*)(W + (size_t)row * 1024 + c8);
    float4 v1 = *(const float4*)(W + (size_t)row * 1024 + c8 + 4);
    p[0] = f2bf(v0.x); p[1] = f2bf(v0.y); p[2] = f2bf(v0.z); p[3] = f2bf(v0.w);
    p[4] = f2bf(v1.x); p[5] = f2bf(v1.y); p[6] = f2bf(v1.z); p[7] = f2bf(v1.w);
  } else if (c8 < 1040) {
#pragma unroll
    for (int j = 0; j < 8; j++) p[j] = f2bf(Bm[(size_t)row * 16 + (c8 - 1024) + j]);
  } else {
#pragma unroll
    for (int j = 0; j < 8; j++) p[j] = 0;
  }
  *(bf16x8*)(Waug + (size_t)row * KAUG + c8) = p;
}

// ---------------------------------------------------------------------------
// 128x128 bf16 MFMA GEMM, K = KAUG, 2-phase double-buffered (T3 minimum
// recipe): per tile issue STAGE(t+1) into buf^1 FIRST, then ds_read+MFMA on
// buf[cur], then ONE vmcnt(0)+barrier at tile end.
// L2-aware XCD mapping: XCD x = blockIdx%8 owns a compact 8m x W n region
// (gemm<0>: 8x12 of 32x24 grid, ~5.5MB working set; gemm<1>: 8x4 of 32x8,
// ~3.3MB) so staging loads hit the XCD-private L2 (~200cy) instead of
// HBM (~900cy); the 1-tile prefetch then covers the latency.
// EPI 0: QKV epilogue; EPI 1: proj epilogue (bias, fp32 out)
template <int EPI>
__global__ __launch_bounds__(256) void gemm_kernel(
    const short* __restrict__ Amat, const short* __restrict__ Bmat,
    const float* __restrict__ bias,
    const float* __restrict__ kv_scale, const float* __restrict__ kv_zp,
    short* __restrict__ Qb, short* __restrict__ Kb, short* __restrict__ Vt,
    float* __restrict__ Out) {
  __shared__ short lds[2 * 2 * 128 * 64];   // [buf][A/B][128*64] = 64 KB
  char* const ldsB = (char*)lds;
  const int tid = threadIdx.x;
  const int lane = tid & 63;
  const int wid = tid >> 6;
  const int wr = wid >> 1, wc = wid & 1;
  const int r16 = lane & 15, g = lane >> 4;

  // L2-aware XCD mapping (bijective; gridDim 768 -> 32x24, 256 -> 32x8)
  const int x = blockIdx.x & 7;
  const int l = blockIdx.x >> 3;
  int bm, bn;
  if (EPI == 0) {
    bm = ((x & 3) * 8 + (l & 7)) * 128;      // l&7 in [0,8)
    bn = (((x >> 2) * 12) + (l >> 3)) * 128; // l>>3 in [0,12)
  } else {
    bm = ((x & 3) * 8 + (l & 7)) * 128;
    bn = (((x >> 2) * 4) + (l >> 3)) * 128;  // l>>3 in [0,4)
  }

  // stage one K-tile (A+B) into buffer `buf`; LDS chunk (row,cs) holds
  // global chunk (row, cs^(row&7)); dest byte = chunkIndex*16 (linear).
  // Buffer stride 32768 B: A at +0, B at +16384.
#define STAGE_TILE(buf, k0)                                                   \
  do {                                                                        \
    _Pragma("unroll") for (int i = 0; i < 4; i++) {                           \
      int L = i * 256 + tid;                                                  \
      int row = L >> 3;                                                       \
      int cg = (L & 7) ^ (row & 7);                                           \
      char* d = ldsB + (buf) * 32768 + (i * 256 + wid * 64) * 16;             \
      gload_lds16(Amat + (size_t)(bm + row) * KAUG + (k0) + cg * 8, d);       \
      gload_lds16(Bmat + (size_t)(bn + row) * KAUG + (k0) + cg * 8,           \
                  d + 16384);                                                 \
    }                                                                         \
  } while (0)

  f32x4 zero = {0.f, 0.f, 0.f, 0.f};
  f32x4 acc[4][4];
#pragma unroll
  for (int i = 0; i < 4; i++)
#pragma unroll
    for (int j = 0; j < 4; j++) acc[i][j] = zero;

  STAGE_TILE(0, 0);
  asm volatile("s_waitcnt vmcnt(0)" ::: "memory");
  __builtin_amdgcn_s_barrier();
  __builtin_amdgcn_sched_barrier(0);

  int cur = 0;
  for (int t = 0; t < NTILES; ++t) {
    if (t + 1 < NTILES) STAGE_TILE(cur ^ 1, (t + 1) * 64);
    __builtin_amdgcn_sched_barrier(0);   // keep prefetch issue ahead of reads
    const char* Ab = ldsB + cur * 32768;
    const char* Bb = Ab + 16384;
#pragma unroll
    for (int kk = 0; kk < 2; kk++) {
      bf16x8 a[4], b[4];
#pragma unroll
      for (int mi = 0; mi < 4; mi++) {
        int row = wr * 64 + mi * 16 + r16;
        int cs = (kk * 4 + g) ^ (row & 7);
        a[mi] = *(const bf16x8*)(Ab + (row * 8 + cs) * 16);
      }
#pragma unroll
      for (int ni = 0; ni < 4; ni++) {
        int row = wc * 64 + ni * 16 + r16;
        int cs = (kk * 4 + g) ^ (row & 7);
        b[ni] = *(const bf16x8*)(Bb + (row * 8 + cs) * 16);
      }
      __builtin_amdgcn_s_setprio(1);
#pragma unroll
      for (int mi = 0; mi < 4; mi++)
#pragma unroll
        for (int ni = 0; ni < 4; ni++)
          acc[mi][ni] = __builtin_amdgcn_mfma_f32_16x16x32_bf16(
              a[mi], b[ni], acc[mi][ni], 0, 0, 0);
      __builtin_amdgcn_s_setprio(0);
    }
    asm volatile("s_waitcnt vmcnt(0)" ::: "memory");
    __builtin_amdgcn_s_barrier();
    __builtin_amdgcn_sched_barrier(0);
    cur ^= 1;
  }
#undef STAGE_TILE

  if (EPI == 0) {
    const float scale = kv_scale[0];
    const float zp = kv_zp[0];
    const int which = bn >> 10;  // 0=Q 1=K 2=V (uniform per block)
#pragma unroll
    for (int mi = 0; mi < 4; mi++)
#pragma unroll
      for (int ni = 0; ni < 4; ni++)
#pragma unroll
        for (int r = 0; r < 4; r++) {
          int m = bm + wr * 64 + mi * 16 + g * 4 + r;
          int n = bn + wc * 64 + ni * 16 + r16;
          float val = acc[mi][ni][r] + bias[n];
          int hn = n & 1023;
          int bhm = (m >> 11) * 16 + (hn >> 6);
          int tq = m & 2047;
          int d = hn & 63;
          if (which == 0) {
            Qb[((size_t)bhm * TT + tq) * 64 + d] =
                f2bf(val * 0.125f * 1.44269504088896340736f);
          } else {
            float q = rintf(val / scale + zp);   // round-half-even like jnp.round
            q = fminf(fmaxf(q, 0.f), 255.f);
            float deq = (q - zp) * scale;
            if (which == 1) Kb[((size_t)bhm * TT + tq) * 64 + d] = f2bf(deq);
            else            Vt[((size_t)bhm * 64 + d) * TT + tq] = f2bf(deq);
          }
        }
  } else {
#pragma unroll
    for (int mi = 0; mi < 4; mi++)
#pragma unroll
      for (int ni = 0; ni < 4; ni++)
#pragma unroll
        for (int r = 0; r < 4; r++) {
          int m = bm + wr * 64 + mi * 16 + g * 4 + r;
          int n = bn + wc * 64 + ni * 16 + r16;
          Out[(size_t)m * CDIM + n] = acc[mi][ni][r] + bias[n];
        }
  }
}

// ---------------------------------------------------------------------------
// Causal flash attention, swapped-operand 32x32x16 MFMA (guide §B), balanced
// q-block pairing + even/odd KV-tile warp split + 2-phase dbuf pipeline.
// 1-D grid of 256; L2-aware XCD mapping: XCD x owns heads bh in [4x,4x+4)
// (4 x 512KB K/V working set fits the 4MB XCD L2).
__global__ __launch_bounds__(512) void attn_kernel(
    const short* __restrict__ Qb, const short* __restrict__ Kb,
    const short* __restrict__ Vt, short* __restrict__ Caug) {
  __shared__ short Kls[4 * 4096];   // 4 bufs x [64 kv][64 d], 32KB, chunk-swizzled
  __shared__ short Vls[4 * 4096];   // 4 bufs x [64 d][64 kv], 32KB, chunk-swizzled
  const int tid = threadIdx.x;
  const int lane = tid & 63;
  const int w = tid >> 6;
  const int qsub = w & 3;
  const int p = w >> 2;
  const int q32 = lane & 31;
  const int hi = lane >> 5;
  const int xid = blockIdx.x & 7;
  const int lix = blockIdx.x >> 3;      // [0,32)
  const int bh = xid * 4 + (lix & 3);   // XCD-local heads
  const int bx = lix >> 2;              // [0,8)
  const size_t kvbase = (size_t)bh * TT * 64;
  const int swz = q32 & 7;
  const int b = bh >> 4, h = bh & 15;

  const int srow = tid >> 3;
  const int scg = (tid & 7) ^ (srow & 7);
  const int sdst = w * 1024;

  for (int seg = 0; seg < 2; seg++) {
    const int qb = seg ? bx : 15 - bx;   // pair (15-bx, bx): 34 tiles total
    const int q0 = qb * 128;
    const int q0w = q0 + qsub * 32;
    const int nt = 2 * qb + 2;
    const int ns = nt >> 1;

    bf16x8 qf[4];
    {
      const short* qp = Qb + kvbase + (size_t)(q0w + q32) * 64;
#pragma unroll
      for (int kd = 0; kd < 4; kd++)
        qf[kd] = *(const bf16x8*)(qp + kd * 16 + hi * 8);
    }
    f32x16 accT[2];
#pragma unroll
    for (int i = 0; i < 16; i++) { accT[0][i] = 0.f; accT[1][i] = 0.f; }
    float m_run = -1e30f, l_run = 0.f;

    // prologue: stage pair 0 into buffers {0,1}
#pragma unroll
    for (int t2 = 0; t2 < 2; t2++) {
      int kv0 = t2 * 64;
      gload_lds16(Kb + kvbase + (size_t)(kv0 + srow) * 64 + scg * 8,
                  (char*)Kls + t2 * 8192 + sdst);
      gload_lds16(Vt + kvbase + (size_t)srow * TT + kv0 + scg * 8,
                  (char*)Vls + t2 * 8192 + sdst);
    }
    asm volatile("s_waitcnt vmcnt(0)" ::: "memory");
    __builtin_amdgcn_s_barrier();
    __builtin_amdgcn_sched_barrier(0);

    for (int s = 0; s < ns; s++) {
      if (s + 1 < ns) {
        const int bp = ((s + 1) & 1) * 2;
#pragma unroll
        for (int t2 = 0; t2 < 2; t2++) {
          int kv0 = (2 * (s + 1) + t2) * 64;
          gload_lds16(Kb + kvbase + (size_t)(kv0 + srow) * 64 + scg * 8,
                      (char*)Kls + (bp + t2) * 8192 + sdst);
          gload_lds16(Vt + kvbase + (size_t)srow * TT + kv0 + scg * 8,
                      (char*)Vls + (bp + t2) * 8192 + sdst);
        }
      }
      const int kv0 = (2 * s + p) * 64;
      if (kv0 <= q0w + 31) {   // warp-uniform causal skip
        const char* Kbase = (const char*)Kls + (2 * (s & 1) + p) * 8192;
        const char* Vbase = (const char*)Vls + (2 * (s & 1) + p) * 8192;
        f32x16 sA, sB;
#pragma unroll
        for (int i = 0; i < 16; i++) { sA[i] = 0.f; sB[i] = 0.f; }
        __builtin_amdgcn_s_setprio(1);
#pragma unroll
        for (int kd = 0; kd < 4; kd++) {
          int coff = ((kd * 2 + hi) ^ swz) * 16;
          bf16x8 a0 = *(const bf16x8*)(Kbase + q32 * 128 + coff);
          bf16x8 a1 = *(const bf16x8*)(Kbase + (32 + q32) * 128 + coff);
          sA = __builtin_amdgcn_mfma_f32_32x32x16_bf16(a0, qf[kd], sA, 0, 0, 0);
          sB = __builtin_amdgcn_mfma_f32_32x32x16_bf16(a1, qf[kd], sB, 0, 0, 0);
        }
        __builtin_amdgcn_s_setprio(0);
        const int qg = q0w + q32;
        if (kv0 + 63 > q0w) {
#pragma unroll
          for (int r = 0; r < 16; r++) {
            int kvr = kv0 + (r & 3) + 8 * (r >> 2) + 4 * hi;
            if (kvr > qg) sA[r] = -1e30f;
            if (kvr + 32 > qg) sB[r] = -1e30f;
          }
        }
        float mx = sA[0];
#pragma unroll
        for (int r = 1; r < 16; r++) mx = fmaxf(mx, sA[r]);
#pragma unroll
        for (int r = 0; r < 16; r++) mx = fmaxf(mx, sB[r]);
        mx = fmaxf(mx, __shfl_xor(mx, 32));
        float mnew = fmaxf(m_run, mx);
        float corr = exp2f(m_run - mnew);
        float rs = 0.f;
#pragma unroll
        for (int r = 0; r < 16; r++) {
          sA[r] = exp2f(sA[r] - mnew);
          sB[r] = exp2f(sB[r] - mnew);
          rs += sA[r] + sB[r];
        }
        rs += __shfl_xor(rs, 32);
        l_run = l_run * corr + rs;
        m_run = mnew;
#pragma unroll
        for (int r = 0; r < 16; r++) { accT[0][r] *= corr; accT[1][r] *= corr; }

        bf16x8 pf[4];
#pragma unroll
        for (int t2 = 0; t2 < 2; t2++) {
#pragma unroll
          for (int s01 = 0; s01 < 2; s01++) {
            int base = 8 * s01;
            unsigned int wlo0, wlo1, whi0, whi1;
            if (t2 == 0) {
              wlo0 = cvt_pk_bf16(sA[base + 0], sA[base + 1]);
              wlo1 = cvt_pk_bf16(sA[base + 2], sA[base + 3]);
              whi0 = cvt_pk_bf16(sA[base + 4], sA[base + 5]);
              whi1 = cvt_pk_bf16(sA[base + 6], sA[base + 7]);
            } else {
              wlo0 = cvt_pk_bf16(sB[base + 0], sB[base + 1]);
              wlo1 = cvt_pk_bf16(sB[base + 2], sB[base + 3]);
              whi0 = cvt_pk_bf16(sB[base + 4], sB[base + 5]);
              whi1 = cvt_pk_bf16(sB[base + 6], sB[base + 7]);
            }
            asm volatile("v_permlane32_swap_b32 %0, %1" : "+v"(wlo0), "+v"(whi0));
            asm volatile("v_permlane32_swap_b32 %0, %1" : "+v"(wlo1), "+v"(whi1));
            union { unsigned int u[4]; bf16x8 v; } cc;
            cc.u[0] = wlo0; cc.u[1] = wlo1; cc.u[2] = whi0; cc.u[3] = whi1;
            pf[t2 * 2 + s01] = cc.v;
          }
        }
        __builtin_amdgcn_s_setprio(1);
#pragma unroll
        for (int db = 0; db < 2; db++) {
          const int row = db * 32 + q32;
#pragma unroll
          for (int ks = 0; ks < 4; ks++) {
            bf16x8 vf = *(const bf16x8*)(Vbase + row * 128 +
                                         (((ks * 2 + hi) ^ swz) * 16));
            accT[db] = __builtin_amdgcn_mfma_f32_32x32x16_bf16(vf, pf[ks],
                                                               accT[db], 0, 0, 0);
          }
        }
        __builtin_amdgcn_s_setprio(0);
      }
      asm volatile("s_waitcnt vmcnt(0) lgkmcnt(0)" ::: "memory");
      __builtin_amdgcn_s_barrier();
      __builtin_amdgcn_sched_barrier(0);
    }

    // merge parity partials through LDS (reuse K/V buffers as scratch)
    float* scrO = (float*)Kls;
    float* scrML = (float*)Vls;
    if (p == 1) {
#pragma unroll
      for (int db = 0; db < 2; db++)
#pragma unroll
        for (int r = 0; r < 16; r++)
          scrO[qsub * 2048 + (db * 16 + r) * 64 + lane] = accT[db][r];
      scrML[qsub * 64 + lane] = m_run;
      scrML[256 + qsub * 64 + lane] = l_run;
    }
    __syncthreads();
    if (p == 0) {
      float m_o = scrML[qsub * 64 + lane];
      float l_o = scrML[256 + qsub * 64 + lane];
      float mm = fmaxf(m_run, m_o);
      float ce = exp2f(m_run - mm), co = exp2f(m_o - mm);
      float lt = l_run * ce + l_o * co;
      float rinv = 1.f / lt;
      short* cp = Caug + (size_t)(b * TT + q0w + q32) * KAUG + h * 64;
#pragma unroll
      for (int db = 0; db < 2; db++)
#pragma unroll
        for (int rg = 0; rg < 4; rg++) {
          short4v pk4;
#pragma unroll
          for (int rr = 0; rr < 4; rr++) {
            int r = rg * 4 + rr;
            float v = accT[db][r] * ce +
                      scrO[qsub * 2048 + (db * 16 + r) * 64 + lane] * co;
            pk4[rr] = f2bf(v * rinv);
          }
          *(short4v*)(cp + db * 32 + rg * 8 + hi * 4) = pk4;
        }
    }
    __syncthreads();
  }
}

// ---------------------------------------------------------------------------
extern "C" void kernel_launch(void* const* d_in, const int* in_sizes, int n_in,
                              void* d_out, int out_size, void* d_ws, size_t ws_size,
                              hipStream_t stream) {
  const float* x       = (const float*)d_in[0];
  const float* W_attn  = (const float*)d_in[1];
  const float* b_attn  = (const float*)d_in[2];
  const float* A_attn  = (const float*)d_in[3];
  const float* B_attn  = (const float*)d_in[4];
  const float* W_proj  = (const float*)d_in[5];
  const float* b_proj  = (const float*)d_in[6];
  const float* A_proj  = (const float*)d_in[7];
  const float* B_proj  = (const float*)d_in[8];
  const float* kv_scale = (const float*)d_in[9];
  const float* kv_zp    = (const float*)d_in[10];
  float* out = (float*)d_out;

  char* p = (char*)d_ws;
  short* Xaug  = (short*)p; p += (size_t)BT * KAUG * 2;
  short* Waug1 = (short*)p; p += (size_t)3072 * KAUG * 2;
  short* Waug2 = (short*)p; p += (size_t)1024 * KAUG * 2;
  short* Caug  = (short*)p; p += (size_t)BT * KAUG * 2;
  short* Qb    = (short*)p; p += (size_t)32 * TT * 64 * 2;
  short* Kb    = (short*)p; p += (size_t)32 * TT * 64 * 2;
  short* Vt    = (short*)p; p += (size_t)32 * TT * 64 * 2;

  rank1_kernel<<<dim3(256), dim3(256), 0, stream>>>(x, A_attn, Xaug);
  packw_kernel<<<dim3(1632), dim3(256), 0, stream>>>(W_attn, B_attn, Waug1, 3072);
  packw_kernel<<<dim3(544), dim3(256), 0, stream>>>(W_proj, B_proj, Waug2, 1024);
  gemm_kernel<0><<<dim3(768), dim3(256), 0, stream>>>(
      Xaug, Waug1, b_attn, kv_scale, kv_zp, Qb, Kb, Vt, (float*)nullptr);
  attn_kernel<<<dim3(256), dim3(512), 0, stream>>>(Qb, Kb, Vt, Caug);
  rank2_kernel<<<dim3(256), dim3(256), 0, stream>>>(A_proj, Caug);
  gemm_kernel<1><<<dim3(256), dim3(256), 0, stream>>>(
      Caug, Waug2, b_proj, kv_scale, kv_zp,
      (short*)nullptr, (short*)nullptr, (short*)nullptr, out);
}

// Round 8
// 147.549 us; speedup vs baseline: 1.4168x; 1.2370x over previous
//
#include <hip/hip_runtime.h>
#include <math.h>

#define TT 2048
#define CDIM 1024
#define BT 4096
#define NT16 16   // K tiles (K = 1024, BK = 64)

typedef __attribute__((ext_vector_type(8))) short bf16x8;
typedef __attribute__((ext_vector_type(4))) short short4v;
typedef __attribute__((ext_vector_type(4))) float f32x4;
typedef __attribute__((ext_vector_type(16))) float f32x16;

static __device__ __forceinline__ short f2bf(float f) {
  union { float f; unsigned int u; } c; c.f = f;
  unsigned int u = c.u;
  u += 0x7fff + ((u >> 16) & 1);   // round-to-nearest-even
  return (short)(u >> 16);
}

static __device__ __forceinline__ void gload_lds16(const void* g, void* l) {
  __builtin_amdgcn_global_load_lds(
      (const __attribute__((address_space(1))) void*)g,
      (__attribute__((address_space(3))) void*)l, 16, 0, 0);
}

static __device__ __forceinline__ unsigned int cvt_pk_bf16(float lo, float hi) {
  unsigned int r;
  asm("v_cvt_pk_bf16_f32 %0, %1, %2" : "=v"(r) : "v"(lo), "v"(hi));
  return r;
}

// ---------------------------------------------------------------------------
// packx: x fp32 -> bf16, flat. 8 elems/thread.
__global__ __launch_bounds__(256) void packx_kernel(
    const float* __restrict__ x, short* __restrict__ Xb) {
  const size_t i = ((size_t)blockIdx.x * 256 + threadIdx.x) * 8;
  float4 v0 = *(const float4*)(x + i);
  float4 v1 = *(const float4*)(x + i + 4);
  bf16x8 p;
  p[0] = f2bf(v0.x); p[1] = f2bf(v0.y); p[2] = f2bf(v0.z); p[3] = f2bf(v0.w);
  p[4] = f2bf(v1.x); p[5] = f2bf(v1.y); p[6] = f2bf(v1.z); p[7] = f2bf(v1.w);
  *(bf16x8*)(Xb + i) = p;
}

// ---------------------------------------------------------------------------
// packw_eff: Weff = W + 2*(B@A), fp32 accum, single bf16 rounding.
// W [rows][1024] f32, Bm [rows][16] f32, Aa [16][1024] f32 -> Waug bf16.
// Block = 2 rows x 128 threads; A staged in LDS (64KB).
__global__ __launch_bounds__(256) void packw_eff_kernel(
    const float* __restrict__ W, const float* __restrict__ Bm,
    const float* __restrict__ Aa, short* __restrict__ Waug) {
  __shared__ float Als[16 * 1024];
  const int tid = threadIdx.x;
  for (int i = tid; i < 4096; i += 256)
    ((float4*)Als)[i] = ((const float4*)Aa)[i];
  __syncthreads();
  const int row = blockIdx.x * 2 + (tid >> 7);
  const int c8 = (tid & 127) * 8;
  float4 w0 = *(const float4*)(W + (size_t)row * 1024 + c8);
  float4 w1 = *(const float4*)(W + (size_t)row * 1024 + c8 + 4);
  float acc[8] = {w0.x, w0.y, w0.z, w0.w, w1.x, w1.y, w1.z, w1.w};
  const float* brow = Bm + (size_t)row * 16;
#pragma unroll
  for (int r = 0; r < 16; r++) {
    float b2 = 2.f * brow[r];
#pragma unroll
    for (int j = 0; j < 8; j++) acc[j] += b2 * Als[r * 1024 + c8 + j];
  }
  bf16x8 p;
#pragma unroll
  for (int j = 0; j < 8; j++) p[j] = f2bf(acc[j]);
  *(bf16x8*)(Waug + (size_t)row * 1024 + c8) = p;
}

// ---------------------------------------------------------------------------
// QKV GEMM: 256x256 tile, K=1024, m201-style 8-phase schedule (T2/T3/T4/T5).
// 512 thr = 8 waves (wr=w>>2 M-half, wc=w&3 N-quarter); per-wave C 128x64.
// LDS 128KB: dbuf d*65536 + {A0,A1,B0,B1}*16384; half = 128 rows x 64 k bf16,
// chunk-XOR swizzled (LDS chunk (row,cs) holds global chunk (row,cs^(row&7))).
// Per K-tile t: 4 phases; phase p: {ds_read A-quad p (+ B subtile at p=0) ||
// stage 1 half-tile of t+1 into dbuf^1 -> barrier -> lgkmcnt(0) -> 16 MFMA ->
// barrier}. ONE vmcnt(2) per K-tile at phase 1 (8 in-flight + 2 new; waits
// tile t's halves, keeps the 2 newest in flight). Last tile waits vmcnt(0).
__global__ __launch_bounds__(512) void gemm256_qkv_kernel(
    const short* __restrict__ Amat, const short* __restrict__ Bmat,
    const float* __restrict__ bias,
    const float* __restrict__ kv_scale, const float* __restrict__ kv_zp,
    short* __restrict__ Qb, short* __restrict__ Kb, short* __restrict__ Vt) {
  __shared__ short lds[65536];   // 128 KB
  char* const ldsB = (char*)lds;
  const int tid = threadIdx.x;
  const int lane = tid & 63;
  const int w = tid >> 6;
  const int wr = w >> 2, wc = w & 3;
  const int r16 = lane & 15, g = lane >> 4;

  // L2-aware XCD mapping: grid 192 = 16m x 12n; XCD x gets 4m x 6n region.
  const int x = blockIdx.x & 7;
  const int l = blockIdx.x >> 3;             // [0,24)
  const int bm = ((x & 3) * 4 + (l & 3)) * 256;
  const int bn = ((x >> 2) * 6 + (l >> 2)) * 256;

  const int srow = tid >> 3;                 // [0,64)
  const int scg = (tid & 7) ^ (srow & 7);
  const int sdst = tid * 16;

#define STAGE_HALF(mat, rowbase, k0, ldsoff)                                  \
  do {                                                                        \
    const short* s_ = (mat) + (size_t)((rowbase) + srow) * CDIM + (k0) +      \
                      scg * 8;                                                \
    char* d_ = ldsB + (ldsoff) + sdst;                                        \
    gload_lds16(s_, d_);                                                      \
    gload_lds16(s_ + (size_t)64 * CDIM, d_ + 8192);                           \
  } while (0)

  f32x4 zero = {0.f, 0.f, 0.f, 0.f};
  f32x4 acc[8][4];
#pragma unroll
  for (int i = 0; i < 8; i++)
#pragma unroll
    for (int j = 0; j < 4; j++) acc[i][j] = zero;

  // prologue: 4 halves of tile 0 into dbuf0 (8 loads/wave in flight)
  STAGE_HALF(Amat, bm, 0, 0);
  STAGE_HALF(Amat, bm + 128, 0, 16384);
  STAGE_HALF(Bmat, bn, 0, 32768);
  STAGE_HALF(Bmat, bn + 128, 0, 49152);

  const int bhalfbase = 32768 + (wc >> 1) * 16384;
  const int browbase = (wc & 1) * 64;

  for (int t = 0; t < NT16; ++t) {
    const int d = (t & 1) << 16;
    const int dn = ((t + 1) & 1) << 16;
    const int k1 = (t + 1) * 64;
    const bool st = (t < NT16 - 1);

    // ---------------- phase 1
    if (st) {
      STAGE_HALF(Amat, bm, k1, dn + 0);
      asm volatile("s_waitcnt vmcnt(2)" ::: "memory");
    } else {
      asm volatile("s_waitcnt vmcnt(0)" ::: "memory");
    }
    __builtin_amdgcn_s_barrier();
    __builtin_amdgcn_sched_barrier(0);

    bf16x8 breg[4][2];
#pragma unroll
    for (int ni = 0; ni < 4; ni++)
#pragma unroll
      for (int kk = 0; kk < 2; kk++) {
        int rowb = browbase + ni * 16 + r16;
        breg[ni][kk] = *(const bf16x8*)(
            ldsB + d + bhalfbase + rowb * 128 +
            (((kk * 4 + g) ^ (rowb & 7)) * 16));
      }
    {
      bf16x8 a0[2][2];
#pragma unroll
      for (int mi2 = 0; mi2 < 2; mi2++)
#pragma unroll
        for (int kk = 0; kk < 2; kk++) {
          int rowa = mi2 * 16 + r16;
          a0[mi2][kk] = *(const bf16x8*)(
              ldsB + d + wr * 16384 + rowa * 128 +
              (((kk * 4 + g) ^ (rowa & 7)) * 16));
        }
      asm volatile("s_waitcnt lgkmcnt(0)" ::: "memory");
      __builtin_amdgcn_sched_barrier(0);
      __builtin_amdgcn_s_setprio(1);
#pragma unroll
      for (int mi2 = 0; mi2 < 2; mi2++)
#pragma unroll
        for (int ni = 0; ni < 4; ni++)
#pragma unroll
          for (int kk = 0; kk < 2; kk++)
            acc[mi2][ni] = __builtin_amdgcn_mfma_f32_16x16x32_bf16(
                a0[mi2][kk], breg[ni][kk], acc[mi2][ni], 0, 0, 0);
      __builtin_amdgcn_s_setprio(0);
      __builtin_amdgcn_s_barrier();
    }

    // ---------------- phases 2..4
#pragma unroll
    for (int p = 1; p < 4; ++p) {
      bf16x8 ap[2][2];
#pragma unroll
      for (int mi2 = 0; mi2 < 2; mi2++)
#pragma unroll
        for (int kk = 0; kk < 2; kk++) {
          int rowa = (2 * p + mi2) * 16 + r16;
          ap[mi2][kk] = *(const bf16x8*)(
              ldsB + d + wr * 16384 + rowa * 128 +
              (((kk * 4 + g) ^ (rowa & 7)) * 16));
        }
      if (st) {
        if (p == 1)      STAGE_HALF(Amat, bm + 128, k1, dn + 16384);
        else if (p == 2) STAGE_HALF(Bmat, bn, k1, dn + 32768);
        else             STAGE_HALF(Bmat, bn + 128, k1, dn + 49152);
      }
      __builtin_amdgcn_s_barrier();
      asm volatile("s_waitcnt lgkmcnt(0)" ::: "memory");
      __builtin_amdgcn_sched_barrier(0);
      __builtin_amdgcn_s_setprio(1);
#pragma unroll
      for (int mi2 = 0; mi2 < 2; mi2++)
#pragma unroll
        for (int ni = 0; ni < 4; ni++)
#pragma unroll
          for (int kk = 0; kk < 2; kk++)
            acc[2 * p + mi2][ni] = __builtin_amdgcn_mfma_f32_16x16x32_bf16(
                ap[mi2][kk], breg[ni][kk], acc[2 * p + mi2][ni], 0, 0, 0);
      __builtin_amdgcn_s_setprio(0);
      __builtin_amdgcn_s_barrier();
    }
  }
#undef STAGE_HALF

  // epilogue (indexing verified in R4): bias, Q scale, fake-quant K/V
  const float scale = kv_scale[0];
  const float zp = kv_zp[0];
  const int which = bn >> 10;  // 0=Q 1=K 2=V (uniform: 256 | 1024)
#pragma unroll
  for (int mi = 0; mi < 8; mi++)
#pragma unroll
    for (int ni = 0; ni < 4; ni++)
#pragma unroll
      for (int r = 0; r < 4; r++) {
        int m = bm + wr * 128 + mi * 16 + g * 4 + r;
        int n = bn + wc * 64 + ni * 16 + r16;
        float val = acc[mi][ni][r] + bias[n];
        int hn = n & 1023;
        int bhm = (m >> 11) * 16 + (hn >> 6);
        int tq = m & 2047;
        int dd = hn & 63;
        if (which == 0) {
          Qb[((size_t)bhm * TT + tq) * 64 + dd] =
              f2bf(val * 0.125f * 1.44269504088896340736f);
        } else {
          float q = rintf(val / scale + zp);   // round-half-even like jnp.round
          q = fminf(fmaxf(q, 0.f), 255.f);
          float deq = (q - zp) * scale;
          if (which == 1) Kb[((size_t)bhm * TT + tq) * 64 + dd] = f2bf(deq);
          else            Vt[((size_t)bhm * 64 + dd) * TT + tq] = f2bf(deq);
        }
      }
}

// ---------------------------------------------------------------------------
// proj GEMM: 128x128, K=1024, 2-phase dbuf (R7 structure, verified).
__global__ __launch_bounds__(256) void gemm_proj_kernel(
    const short* __restrict__ Amat, const short* __restrict__ Bmat,
    const float* __restrict__ bias, float* __restrict__ Out) {
  __shared__ short lds[2 * 2 * 128 * 64];   // 64 KB
  char* const ldsB = (char*)lds;
  const int tid = threadIdx.x;
  const int lane = tid & 63;
  const int wid = tid >> 6;
  const int wr = wid >> 1, wc = wid & 1;
  const int r16 = lane & 15, g = lane >> 4;

  // L2-aware XCD mapping (grid 256 = 32m x 8n; XCD x gets 8m x 4n)
  const int x = blockIdx.x & 7;
  const int l = blockIdx.x >> 3;
  const int bm = ((x & 3) * 8 + (l & 7)) * 128;
  const int bn = (((x >> 2) * 4) + (l >> 3)) * 128;

#define STAGE_TILE(buf, k0)                                                   \
  do {                                                                        \
    _Pragma("unroll") for (int i = 0; i < 4; i++) {                           \
      int L = i * 256 + tid;                                                  \
      int row = L >> 3;                                                       \
      int cg = (L & 7) ^ (row & 7);                                           \
      char* d = ldsB + (buf) * 32768 + (i * 256 + wid * 64) * 16;             \
      gload_lds16(Amat + (size_t)(bm + row) * CDIM + (k0) + cg * 8, d);       \
      gload_lds16(Bmat + (size_t)(bn + row) * CDIM + (k0) + cg * 8,           \
                  d + 16384);                                                 \
    }                                                                         \
  } while (0)

  f32x4 zero = {0.f, 0.f, 0.f, 0.f};
  f32x4 acc[4][4];
#pragma unroll
  for (int i = 0; i < 4; i++)
#pragma unroll
    for (int j = 0; j < 4; j++) acc[i][j] = zero;

  STAGE_TILE(0, 0);
  asm volatile("s_waitcnt vmcnt(0)" ::: "memory");
  __builtin_amdgcn_s_barrier();
  __builtin_amdgcn_sched_barrier(0);

  int cur = 0;
  for (int t = 0; t < NT16; ++t) {
    if (t + 1 < NT16) STAGE_TILE(cur ^ 1, (t + 1) * 64);
    __builtin_amdgcn_sched_barrier(0);
    const char* Ab = ldsB + cur * 32768;
    const char* Bb = Ab + 16384;
#pragma unroll
    for (int kk = 0; kk < 2; kk++) {
      bf16x8 a[4], b[4];
#pragma unroll
      for (int mi = 0; mi < 4; mi++) {
        int row = wr * 64 + mi * 16 + r16;
        int cs = (kk * 4 + g) ^ (row & 7);
        a[mi] = *(const bf16x8*)(Ab + (row * 8 + cs) * 16);
      }
#pragma unroll
      for (int ni = 0; ni < 4; ni++) {
        int row = wc * 64 + ni * 16 + r16;
        int cs = (kk * 4 + g) ^ (row & 7);
        b[ni] = *(const bf16x8*)(Bb + (row * 8 + cs) * 16);
      }
      __builtin_amdgcn_s_setprio(1);
#pragma unroll
      for (int mi = 0; mi < 4; mi++)
#pragma unroll
        for (int ni = 0; ni < 4; ni++)
          acc[mi][ni] = __builtin_amdgcn_mfma_f32_16x16x32_bf16(
              a[mi], b[ni], acc[mi][ni], 0, 0, 0);
      __builtin_amdgcn_s_setprio(0);
    }
    asm volatile("s_waitcnt vmcnt(0)" ::: "memory");
    __builtin_amdgcn_s_barrier();
    __builtin_amdgcn_sched_barrier(0);
    cur ^= 1;
  }
#undef STAGE_TILE

#pragma unroll
  for (int mi = 0; mi < 4; mi++)
#pragma unroll
    for (int ni = 0; ni < 4; ni++)
#pragma unroll
      for (int r = 0; r < 4; r++) {
        int m = bm + wr * 64 + mi * 16 + g * 4 + r;
        int n = bn + wc * 64 + ni * 16 + r16;
        Out[(size_t)m * CDIM + n] = acc[mi][ni][r] + bias[n];
      }
}

// ---------------------------------------------------------------------------
// Causal flash attention (R7 structure, verified) — writes ctx to Cb
// at row stride CDIM (1024).
__global__ __launch_bounds__(512) void attn_kernel(
    const short* __restrict__ Qb, const short* __restrict__ Kb,
    const short* __restrict__ Vt, short* __restrict__ Cb) {
  __shared__ short Kls[4 * 4096];
  __shared__ short Vls[4 * 4096];
  const int tid = threadIdx.x;
  const int lane = tid & 63;
  const int w = tid >> 6;
  const int qsub = w & 3;
  const int p = w >> 2;
  const int q32 = lane & 31;
  const int hi = lane >> 5;
  const int xid = blockIdx.x & 7;
  const int lix = blockIdx.x >> 3;
  const int bh = xid * 4 + (lix & 3);
  const int bx = lix >> 2;
  const size_t kvbase = (size_t)bh * TT * 64;
  const int swz = q32 & 7;
  const int b = bh >> 4, h = bh & 15;

  const int srow = tid >> 3;
  const int scg = (tid & 7) ^ (srow & 7);
  const int sdst = w * 1024;

  for (int seg = 0; seg < 2; seg++) {
    const int qb = seg ? bx : 15 - bx;
    const int q0 = qb * 128;
    const int q0w = q0 + qsub * 32;
    const int ns = qb + 1;

    bf16x8 qf[4];
    {
      const short* qp = Qb + kvbase + (size_t)(q0w + q32) * 64;
#pragma unroll
      for (int kd = 0; kd < 4; kd++)
        qf[kd] = *(const bf16x8*)(qp + kd * 16 + hi * 8);
    }
    f32x16 accT[2];
#pragma unroll
    for (int i = 0; i < 16; i++) { accT[0][i] = 0.f; accT[1][i] = 0.f; }
    float m_run = -1e30f, l_run = 0.f;

#pragma unroll
    for (int t2 = 0; t2 < 2; t2++) {
      int kv0 = t2 * 64;
      gload_lds16(Kb + kvbase + (size_t)(kv0 + srow) * 64 + scg * 8,
                  (char*)Kls + t2 * 8192 + sdst);
      gload_lds16(Vt + kvbase + (size_t)srow * TT + kv0 + scg * 8,
                  (char*)Vls + t2 * 8192 + sdst);
    }
    asm volatile("s_waitcnt vmcnt(0)" ::: "memory");
    __builtin_amdgcn_s_barrier();
    __builtin_amdgcn_sched_barrier(0);

    for (int s = 0; s < ns; s++) {
      if (s + 1 < ns) {
        const int bp = ((s + 1) & 1) * 2;
#pragma unroll
        for (int t2 = 0; t2 < 2; t2++) {
          int kv0 = (2 * (s + 1) + t2) * 64;
          gload_lds16(Kb + kvbase + (size_t)(kv0 + srow) * 64 + scg * 8,
                      (char*)Kls + (bp + t2) * 8192 + sdst);
          gload_lds16(Vt + kvbase + (size_t)srow * TT + kv0 + scg * 8,
                      (char*)Vls + (bp + t2) * 8192 + sdst);
        }
      }
      const int kv0 = (2 * s + p) * 64;
      if (kv0 <= q0w + 31) {
        const char* Kbase = (const char*)Kls + (2 * (s & 1) + p) * 8192;
        const char* Vbase = (const char*)Vls + (2 * (s & 1) + p) * 8192;
        f32x16 sA, sB;
#pragma unroll
        for (int i = 0; i < 16; i++) { sA[i] = 0.f; sB[i] = 0.f; }
        __builtin_amdgcn_s_setprio(1);
#pragma unroll
        for (int kd = 0; kd < 4; kd++) {
          int coff = ((kd * 2 + hi) ^ swz) * 16;
          bf16x8 a0 = *(const bf16x8*)(Kbase + q32 * 128 + coff);
          bf16x8 a1 = *(const bf16x8*)(Kbase + (32 + q32) * 128 + coff);
          sA = __builtin_amdgcn_mfma_f32_32x32x16_bf16(a0, qf[kd], sA, 0, 0, 0);
          sB = __builtin_amdgcn_mfma_f32_32x32x16_bf16(a1, qf[kd], sB, 0, 0, 0);
        }
        __builtin_amdgcn_s_setprio(0);
        const int qg = q0w + q32;
        if (kv0 + 63 > q0w) {
#pragma unroll
          for (int r = 0; r < 16; r++) {
            int kvr = kv0 + (r & 3) + 8 * (r >> 2) + 4 * hi;
            if (kvr > qg) sA[r] = -1e30f;
            if (kvr + 32 > qg) sB[r] = -1e30f;
          }
        }
        float mx = sA[0];
#pragma unroll
        for (int r = 1; r < 16; r++) mx = fmaxf(mx, sA[r]);
#pragma unroll
        for (int r = 0; r < 16; r++) mx = fmaxf(mx, sB[r]);
        mx = fmaxf(mx, __shfl_xor(mx, 32));
        float mnew = fmaxf(m_run, mx);
        float corr = exp2f(m_run - mnew);
        float rs = 0.f;
#pragma unroll
        for (int r = 0; r < 16; r++) {
          sA[r] = exp2f(sA[r] - mnew);
          sB[r] = exp2f(sB[r] - mnew);
          rs += sA[r] + sB[r];
        }
        rs += __shfl_xor(rs, 32);
        l_run = l_run * corr + rs;
        m_run = mnew;
#pragma unroll
        for (int r = 0; r < 16; r++) { accT[0][r] *= corr; accT[1][r] *= corr; }

        bf16x8 pf[4];
#pragma unroll
        for (int t2 = 0; t2 < 2; t2++) {
#pragma unroll
          for (int s01 = 0; s01 < 2; s01++) {
            int base = 8 * s01;
            unsigned int wlo0, wlo1, whi0, whi1;
            if (t2 == 0) {
              wlo0 = cvt_pk_bf16(sA[base + 0], sA[base + 1]);
              wlo1 = cvt_pk_bf16(sA[base + 2], sA[base + 3]);
              whi0 = cvt_pk_bf16(sA[base + 4], sA[base + 5]);
              whi1 = cvt_pk_bf16(sA[base + 6], sA[base + 7]);
            } else {
              wlo0 = cvt_pk_bf16(sB[base + 0], sB[base + 1]);
              wlo1 = cvt_pk_bf16(sB[base + 2], sB[base + 3]);
              whi0 = cvt_pk_bf16(sB[base + 4], sB[base + 5]);
              whi1 = cvt_pk_bf16(sB[base + 6], sB[base + 7]);
            }
            asm volatile("v_permlane32_swap_b32 %0, %1" : "+v"(wlo0), "+v"(whi0));
            asm volatile("v_permlane32_swap_b32 %0, %1" : "+v"(wlo1), "+v"(whi1));
            union { unsigned int u[4]; bf16x8 v; } cc;
            cc.u[0] = wlo0; cc.u[1] = wlo1; cc.u[2] = whi0; cc.u[3] = whi1;
            pf[t2 * 2 + s01] = cc.v;
          }
        }
        __builtin_amdgcn_s_setprio(1);
#pragma unroll
        for (int db = 0; db < 2; db++) {
          const int row = db * 32 + q32;
#pragma unroll
          for (int ks = 0; ks < 4; ks++) {
            bf16x8 vf = *(const bf16x8*)(Vbase + row * 128 +
                                         (((ks * 2 + hi) ^ swz) * 16));
            accT[db] = __builtin_amdgcn_mfma_f32_32x32x16_bf16(vf, pf[ks],
                                                               accT[db], 0, 0, 0);
          }
        }
        __builtin_amdgcn_s_setprio(0);
      }
      asm volatile("s_waitcnt vmcnt(0) lgkmcnt(0)" ::: "memory");
      __builtin_amdgcn_s_barrier();
      __builtin_amdgcn_sched_barrier(0);
    }

    float* scrO = (float*)Kls;
    float* scrML = (float*)Vls;
    if (p == 1) {
#pragma unroll
      for (int db = 0; db < 2; db++)
#pragma unroll
        for (int r = 0; r < 16; r++)
          scrO[qsub * 2048 + (db * 16 + r) * 64 + lane] = accT[db][r];
      scrML[qsub * 64 + lane] = m_run;
      scrML[256 + qsub * 64 + lane] = l_run;
    }
    __syncthreads();
    if (p == 0) {
      float m_o = scrML[qsub * 64 + lane];
      float l_o = scrML[256 + qsub * 64 + lane];
      float mm = fmaxf(m_run, m_o);
      float ce = exp2f(m_run - mm), co = exp2f(m_o - mm);
      float lt = l_run * ce + l_o * co;
      float rinv = 1.f / lt;
      short* cp = Cb + (size_t)(b * TT + q0w + q32) * CDIM + h * 64;
#pragma unroll
      for (int db = 0; db < 2; db++)
#pragma unroll
        for (int rg = 0; rg < 4; rg++) {
          short4v pk4;
#pragma unroll
          for (int rr = 0; rr < 4; rr++) {
            int r = rg * 4 + rr;
            float v = accT[db][r] * ce +
                      scrO[qsub * 2048 + (db * 16 + r) * 64 + lane] * co;
            pk4[rr] = f2bf(v * rinv);
          }
          *(short4v*)(cp + db * 32 + rg * 8 + hi * 4) = pk4;
        }
    }
    __syncthreads();
  }
}

// ---------------------------------------------------------------------------
extern "C" void kernel_launch(void* const* d_in, const int* in_sizes, int n_in,
                              void* d_out, int out_size, void* d_ws, size_t ws_size,
                              hipStream_t stream) {
  const float* x       = (const float*)d_in[0];
  const float* W_attn  = (const float*)d_in[1];
  const float* b_attn  = (const float*)d_in[2];
  const float* A_attn  = (const float*)d_in[3];
  const float* B_attn  = (const float*)d_in[4];
  const float* W_proj  = (const float*)d_in[5];
  const float* b_proj  = (const float*)d_in[6];
  const float* A_proj  = (const float*)d_in[7];
  const float* B_proj  = (const float*)d_in[8];
  const float* kv_scale = (const float*)d_in[9];
  const float* kv_zp    = (const float*)d_in[10];
  float* out = (float*)d_out;

  char* p = (char*)d_ws;
  short* Xb    = (short*)p; p += (size_t)BT * CDIM * 2;
  short* Waug1 = (short*)p; p += (size_t)3072 * CDIM * 2;
  short* Waug2 = (short*)p; p += (size_t)1024 * CDIM * 2;
  short* Cb    = (short*)p; p += (size_t)BT * CDIM * 2;
  short* Qb    = (short*)p; p += (size_t)32 * TT * 64 * 2;
  short* Kb    = (short*)p; p += (size_t)32 * TT * 64 * 2;
  short* Vt    = (short*)p; p += (size_t)32 * TT * 64 * 2;

  packx_kernel<<<dim3(2048), dim3(256), 0, stream>>>(x, Xb);
  packw_eff_kernel<<<dim3(1536), dim3(256), 0, stream>>>(
      W_attn, B_attn, A_attn, Waug1);
  packw_eff_kernel<<<dim3(512), dim3(256), 0, stream>>>(
      W_proj, B_proj, A_proj, Waug2);
  gemm256_qkv_kernel<<<dim3(192), dim3(512), 0, stream>>>(
      Xb, Waug1, b_attn, kv_scale, kv_zp, Qb, Kb, Vt);
  attn_kernel<<<dim3(256), dim3(512), 0, stream>>>(Qb, Kb, Vt, Cb);
  gemm_proj_kernel<<<dim3(256), dim3(256), 0, stream>>>(
      Cb, Waug2, b_proj, out);
}

// Round 9
// 134.805 us; speedup vs baseline: 1.5508x; 1.0945x over previous
//
#include <hip/hip_runtime.h>
#include <math.h>

#define TT 2048
#define CDIM 1024
#define BT 4096
#define NT16 16   // K tiles (K = 1024, BK = 64)

typedef __attribute__((ext_vector_type(8))) short bf16x8;
typedef __attribute__((ext_vector_type(4))) short short4v;
typedef __attribute__((ext_vector_type(4))) float f32x4;
typedef __attribute__((ext_vector_type(16))) float f32x16;

static __device__ __forceinline__ short f2bf(float f) {
  union { float f; unsigned int u; } c; c.f = f;
  unsigned int u = c.u;
  u += 0x7fff + ((u >> 16) & 1);   // round-to-nearest-even
  return (short)(u >> 16);
}

static __device__ __forceinline__ void gload_lds16(const void* g, void* l) {
  __builtin_amdgcn_global_load_lds(
      (const __attribute__((address_space(1))) void*)g,
      (__attribute__((address_space(3))) void*)l, 16, 0, 0);
}

static __device__ __forceinline__ unsigned int cvt_pk_bf16(float lo, float hi) {
  unsigned int r;
  asm("v_cvt_pk_bf16_f32 %0, %1, %2" : "=v"(r) : "v"(lo), "v"(hi));
  return r;
}

// ---------------------------------------------------------------------------
// packx: x fp32 -> bf16, flat. 8 elems/thread.
__global__ __launch_bounds__(256) void packx_kernel(
    const float* __restrict__ x, short* __restrict__ Xb) {
  const size_t i = ((size_t)blockIdx.x * 256 + threadIdx.x) * 8;
  float4 v0 = *(const float4*)(x + i);
  float4 v1 = *(const float4*)(x + i + 4);
  bf16x8 p;
  p[0] = f2bf(v0.x); p[1] = f2bf(v0.y); p[2] = f2bf(v0.z); p[3] = f2bf(v0.w);
  p[4] = f2bf(v1.x); p[5] = f2bf(v1.y); p[6] = f2bf(v1.z); p[7] = f2bf(v1.w);
  *(bf16x8*)(Xb + i) = p;
}

// ---------------------------------------------------------------------------
// packw_eff: Weff = W + 2*(B@A), fp32 accum, single bf16 rounding.
__global__ __launch_bounds__(256) void packw_eff_kernel(
    const float* __restrict__ W, const float* __restrict__ Bm,
    const float* __restrict__ Aa, short* __restrict__ Waug) {
  __shared__ float Als[16 * 1024];
  const int tid = threadIdx.x;
  for (int i = tid; i < 4096; i += 256)
    ((float4*)Als)[i] = ((const float4*)Aa)[i];
  __syncthreads();
  const int row = blockIdx.x * 2 + (tid >> 7);
  const int c8 = (tid & 127) * 8;
  float4 w0 = *(const float4*)(W + (size_t)row * 1024 + c8);
  float4 w1 = *(const float4*)(W + (size_t)row * 1024 + c8 + 4);
  float acc[8] = {w0.x, w0.y, w0.z, w0.w, w1.x, w1.y, w1.z, w1.w};
  const float* brow = Bm + (size_t)row * 16;
#pragma unroll
  for (int r = 0; r < 16; r++) {
    float b2 = 2.f * brow[r];
#pragma unroll
    for (int j = 0; j < 8; j++) acc[j] += b2 * Als[r * 1024 + c8 + j];
  }
  bf16x8 p;
#pragma unroll
  for (int j = 0; j < 8; j++) p[j] = f2bf(acc[j]);
  *(bf16x8*)(Waug + (size_t)row * 1024 + c8) = p;
}

// ---------------------------------------------------------------------------
// QKV GEMM: 128x128 tile, K=1024, staggered-unit counted-vmcnt pipeline.
// 256 thr = 4 waves; per-wave C 64x64 (wr=wid>>1 M-half, wc=wid&1 N-half).
// LDS 64KB: 2 dbuf x {A 16KB, B 16KB}; stage unit = 32 rows (1 gload/thread).
// Per K-tile t (data in buf[t&1]): 4 phases over mi; stage units of t+1 into
// buf^1 with issue->use distance 2-4 phases:
//   ph1: stage A0,A2(t+1); vmcnt(4); barrier; read breg(all)+a(mi0); 8 MFMA
//   ph2: stage B0,B2(t+1);                    read a(mi1);           8 MFMA
//   ph3: stage B1,B3(t+1); vmcnt(6); barrier; read a(mi2);           8 MFMA
//   ph4: stage A1,A3(t+1);                    read a(mi3);           8 MFMA
// Ledger (loads, FIFO): ph1 wait leaves {A1A3(t), A0A2(t+1)} = 4; ph3 wait
// leaves {A0A2,B0B2,B1B3}(t+1) = 6. Last tile: vmcnt(2)/vmcnt(0).
__global__ __launch_bounds__(256) void gemm_qkv_kernel(
    const short* __restrict__ Amat, const short* __restrict__ Bmat,
    const float* __restrict__ bias,
    const float* __restrict__ kv_scale, const float* __restrict__ kv_zp,
    short* __restrict__ Qb, short* __restrict__ Kb, short* __restrict__ Vt) {
  __shared__ short lds[2 * 2 * 128 * 64];   // 64 KB
  char* const ldsB = (char*)lds;
  const int tid = threadIdx.x;
  const int lane = tid & 63;
  const int wid = tid >> 6;
  const int wr = wid >> 1, wc = wid & 1;
  const int r16 = lane & 15, g = lane >> 4;

  // L2-aware XCD mapping (grid 768 = 32m x 24n; XCD x gets 8m x 12n)
  const int x = blockIdx.x & 7;
  const int l = blockIdx.x >> 3;
  const int bm = ((x & 3) * 8 + (l & 7)) * 128;
  const int bn = (((x >> 2) * 12) + (l >> 3)) * 128;

  // unit i covers rows [32i, 32i+32) of a 128x64 operand tile.
#define STAGE_U(mat, rowbase, k0, i, buf, off)                                \
  do {                                                                        \
    int L_ = (i) * 256 + tid;                                                 \
    int row_ = L_ >> 3;                                                       \
    int cg_ = (L_ & 7) ^ (row_ & 7);                                          \
    gload_lds16((mat) + (size_t)((rowbase) + row_) * CDIM + (k0) + cg_ * 8,   \
                ldsB + (buf) * 32768 + (off) + (i) * 4096 + wid * 1024);      \
  } while (0)
#define STAGE_A(i, buf, k0) STAGE_U(Amat, bm, k0, i, buf, 0)
#define STAGE_B(i, buf, k0) STAGE_U(Bmat, bn, k0, i, buf, 16384)

  f32x4 zero = {0.f, 0.f, 0.f, 0.f};
  f32x4 acc[4][4];
#pragma unroll
  for (int i = 0; i < 4; i++)
#pragma unroll
    for (int j = 0; j < 4; j++) acc[i][j] = zero;

  // prologue: tile 0 into buf0, in ledger order [A0A2][B0B2][B1B3][A1A3]
  STAGE_A(0, 0, 0); STAGE_A(2, 0, 0);
  STAGE_B(0, 0, 0); STAGE_B(2, 0, 0);
  STAGE_B(1, 0, 0); STAGE_B(3, 0, 0);
  STAGE_A(1, 0, 0); STAGE_A(3, 0, 0);

  for (int t = 0; t < NT16; ++t) {
    const int cur = t & 1;
    const int nxt = cur ^ 1;
    const int k1 = (t + 1) * 64;
    const bool st = (t + 1 < NT16);
    const char* Ab = ldsB + cur * 32768;
    const char* Bb = Ab + 16384;

    // ---------------- ph1 (mi = 0)
    if (st) {
      STAGE_A(0, nxt, k1); STAGE_A(2, nxt, k1);
      asm volatile("s_waitcnt vmcnt(4)" ::: "memory");
    } else {
      asm volatile("s_waitcnt vmcnt(2)" ::: "memory");
    }
    __builtin_amdgcn_s_barrier();
    __builtin_amdgcn_sched_barrier(0);

    bf16x8 breg[4][2];
#pragma unroll
    for (int ni = 0; ni < 4; ni++)
#pragma unroll
      for (int kk = 0; kk < 2; kk++) {
        int row = wc * 64 + ni * 16 + r16;
        int cs = (kk * 4 + g) ^ (row & 7);
        breg[ni][kk] = *(const bf16x8*)(Bb + (row * 8 + cs) * 16);
      }
    {
      bf16x8 a0[2];
#pragma unroll
      for (int kk = 0; kk < 2; kk++) {
        int row = wr * 64 + r16;
        int cs = (kk * 4 + g) ^ (row & 7);
        a0[kk] = *(const bf16x8*)(Ab + (row * 8 + cs) * 16);
      }
      asm volatile("s_waitcnt lgkmcnt(0)" ::: "memory");
      __builtin_amdgcn_sched_barrier(0);
      __builtin_amdgcn_s_setprio(1);
#pragma unroll
      for (int ni = 0; ni < 4; ni++)
#pragma unroll
        for (int kk = 0; kk < 2; kk++)
          acc[0][ni] = __builtin_amdgcn_mfma_f32_16x16x32_bf16(
              a0[kk], breg[ni][kk], acc[0][ni], 0, 0, 0);
      __builtin_amdgcn_s_setprio(0);
    }

    // ---------------- ph2 (mi = 1)
    if (st) { STAGE_B(0, nxt, k1); STAGE_B(2, nxt, k1); }
    {
      bf16x8 a1[2];
#pragma unroll
      for (int kk = 0; kk < 2; kk++) {
        int row = wr * 64 + 16 + r16;
        int cs = (kk * 4 + g) ^ (row & 7);
        a1[kk] = *(const bf16x8*)(Ab + (row * 8 + cs) * 16);
      }
      asm volatile("s_waitcnt lgkmcnt(0)" ::: "memory");
      __builtin_amdgcn_sched_barrier(0);
      __builtin_amdgcn_s_setprio(1);
#pragma unroll
      for (int ni = 0; ni < 4; ni++)
#pragma unroll
        for (int kk = 0; kk < 2; kk++)
          acc[1][ni] = __builtin_amdgcn_mfma_f32_16x16x32_bf16(
              a1[kk], breg[ni][kk], acc[1][ni], 0, 0, 0);
      __builtin_amdgcn_s_setprio(0);
    }

    // ---------------- ph3 (mi = 2)
    if (st) {
      STAGE_B(1, nxt, k1); STAGE_B(3, nxt, k1);
      asm volatile("s_waitcnt vmcnt(6)" ::: "memory");
    } else {
      asm volatile("s_waitcnt vmcnt(0)" ::: "memory");
    }
    __builtin_amdgcn_s_barrier();
    __builtin_amdgcn_sched_barrier(0);
    {
      bf16x8 a2[2];
#pragma unroll
      for (int kk = 0; kk < 2; kk++) {
        int row = wr * 64 + 32 + r16;
        int cs = (kk * 4 + g) ^ (row & 7);
        a2[kk] = *(const bf16x8*)(Ab + (row * 8 + cs) * 16);
      }
      asm volatile("s_waitcnt lgkmcnt(0)" ::: "memory");
      __builtin_amdgcn_sched_barrier(0);
      __builtin_amdgcn_s_setprio(1);
#pragma unroll
      for (int ni = 0; ni < 4; ni++)
#pragma unroll
        for (int kk = 0; kk < 2; kk++)
          acc[2][ni] = __builtin_amdgcn_mfma_f32_16x16x32_bf16(
              a2[kk], breg[ni][kk], acc[2][ni], 0, 0, 0);
      __builtin_amdgcn_s_setprio(0);
    }

    // ---------------- ph4 (mi = 3)
    if (st) { STAGE_A(1, nxt, k1); STAGE_A(3, nxt, k1); }
    {
      bf16x8 a3[2];
#pragma unroll
      for (int kk = 0; kk < 2; kk++) {
        int row = wr * 64 + 48 + r16;
        int cs = (kk * 4 + g) ^ (row & 7);
        a3[kk] = *(const bf16x8*)(Ab + (row * 8 + cs) * 16);
      }
      asm volatile("s_waitcnt lgkmcnt(0)" ::: "memory");
      __builtin_amdgcn_sched_barrier(0);
      __builtin_amdgcn_s_setprio(1);
#pragma unroll
      for (int ni = 0; ni < 4; ni++)
#pragma unroll
        for (int kk = 0; kk < 2; kk++)
          acc[3][ni] = __builtin_amdgcn_mfma_f32_16x16x32_bf16(
              a3[kk], breg[ni][kk], acc[3][ni], 0, 0, 0);
      __builtin_amdgcn_s_setprio(0);
    }
  }
#undef STAGE_A
#undef STAGE_B
#undef STAGE_U

  // epilogue (verified R4/R7): bias, Q scale, fake-quant K/V, V transposed
  const float scale = kv_scale[0];
  const float zp = kv_zp[0];
  const int which = bn >> 10;  // 0=Q 1=K 2=V (uniform per block)
#pragma unroll
  for (int mi = 0; mi < 4; mi++)
#pragma unroll
    for (int ni = 0; ni < 4; ni++)
#pragma unroll
      for (int r = 0; r < 4; r++) {
        int m = bm + wr * 64 + mi * 16 + g * 4 + r;
        int n = bn + wc * 64 + ni * 16 + r16;
        float val = acc[mi][ni][r] + bias[n];
        int hn = n & 1023;
        int bhm = (m >> 11) * 16 + (hn >> 6);
        int tq = m & 2047;
        int dd = hn & 63;
        if (which == 0) {
          Qb[((size_t)bhm * TT + tq) * 64 + dd] =
              f2bf(val * 0.125f * 1.44269504088896340736f);
        } else {
          float q = rintf(val / scale + zp);   // round-half-even like jnp.round
          q = fminf(fmaxf(q, 0.f), 255.f);
          float deq = (q - zp) * scale;
          if (which == 1) Kb[((size_t)bhm * TT + tq) * 64 + dd] = f2bf(deq);
          else            Vt[((size_t)bhm * 64 + dd) * TT + tq] = f2bf(deq);
        }
      }
}

// ---------------------------------------------------------------------------
// proj GEMM: 128x128, K=1024, 2-phase dbuf (verified R8 structure).
__global__ __launch_bounds__(256) void gemm_proj_kernel(
    const short* __restrict__ Amat, const short* __restrict__ Bmat,
    const float* __restrict__ bias, float* __restrict__ Out) {
  __shared__ short lds[2 * 2 * 128 * 64];   // 64 KB
  char* const ldsB = (char*)lds;
  const int tid = threadIdx.x;
  const int lane = tid & 63;
  const int wid = tid >> 6;
  const int wr = wid >> 1, wc = wid & 1;
  const int r16 = lane & 15, g = lane >> 4;

  const int x = blockIdx.x & 7;
  const int l = blockIdx.x >> 3;
  const int bm = ((x & 3) * 8 + (l & 7)) * 128;
  const int bn = (((x >> 2) * 4) + (l >> 3)) * 128;

#define STAGE_TILE(buf, k0)                                                   \
  do {                                                                        \
    _Pragma("unroll") for (int i = 0; i < 4; i++) {                           \
      int L = i * 256 + tid;                                                  \
      int row = L >> 3;                                                       \
      int cg = (L & 7) ^ (row & 7);                                           \
      char* d = ldsB + (buf) * 32768 + (i * 256 + wid * 64) * 16;             \
      gload_lds16(Amat + (size_t)(bm + row) * CDIM + (k0) + cg * 8, d);       \
      gload_lds16(Bmat + (size_t)(bn + row) * CDIM + (k0) + cg * 8,           \
                  d + 16384);                                                 \
    }                                                                         \
  } while (0)

  f32x4 zero = {0.f, 0.f, 0.f, 0.f};
  f32x4 acc[4][4];
#pragma unroll
  for (int i = 0; i < 4; i++)
#pragma unroll
    for (int j = 0; j < 4; j++) acc[i][j] = zero;

  STAGE_TILE(0, 0);
  asm volatile("s_waitcnt vmcnt(0)" ::: "memory");
  __builtin_amdgcn_s_barrier();
  __builtin_amdgcn_sched_barrier(0);

  int cur = 0;
  for (int t = 0; t < NT16; ++t) {
    if (t + 1 < NT16) STAGE_TILE(cur ^ 1, (t + 1) * 64);
    __builtin_amdgcn_sched_barrier(0);
    const char* Ab = ldsB + cur * 32768;
    const char* Bb = Ab + 16384;
#pragma unroll
    for (int kk = 0; kk < 2; kk++) {
      bf16x8 a[4], b[4];
#pragma unroll
      for (int mi = 0; mi < 4; mi++) {
        int row = wr * 64 + mi * 16 + r16;
        int cs = (kk * 4 + g) ^ (row & 7);
        a[mi] = *(const bf16x8*)(Ab + (row * 8 + cs) * 16);
      }
#pragma unroll
      for (int ni = 0; ni < 4; ni++) {
        int row = wc * 64 + ni * 16 + r16;
        int cs = (kk * 4 + g) ^ (row & 7);
        b[ni] = *(const bf16x8*)(Bb + (row * 8 + cs) * 16);
      }
      __builtin_amdgcn_s_setprio(1);
#pragma unroll
      for (int mi = 0; mi < 4; mi++)
#pragma unroll
        for (int ni = 0; ni < 4; ni++)
          acc[mi][ni] = __builtin_amdgcn_mfma_f32_16x16x32_bf16(
              a[mi], b[ni], acc[mi][ni], 0, 0, 0);
      __builtin_amdgcn_s_setprio(0);
    }
    asm volatile("s_waitcnt vmcnt(0)" ::: "memory");
    __builtin_amdgcn_s_barrier();
    __builtin_amdgcn_sched_barrier(0);
    cur ^= 1;
  }
#undef STAGE_TILE

#pragma unroll
  for (int mi = 0; mi < 4; mi++)
#pragma unroll
    for (int ni = 0; ni < 4; ni++)
#pragma unroll
      for (int r = 0; r < 4; r++) {
        int m = bm + wr * 64 + mi * 16 + g * 4 + r;
        int n = bn + wc * 64 + ni * 16 + r16;
        Out[(size_t)m * CDIM + n] = acc[mi][ni][r] + bias[n];
      }
}

// ---------------------------------------------------------------------------
// Causal flash attention (verified R7/R8 structure) — ctx to Cb, stride CDIM.
__global__ __launch_bounds__(512) void attn_kernel(
    const short* __restrict__ Qb, const short* __restrict__ Kb,
    const short* __restrict__ Vt, short* __restrict__ Cb) {
  __shared__ short Kls[4 * 4096];
  __shared__ short Vls[4 * 4096];
  const int tid = threadIdx.x;
  const int lane = tid & 63;
  const int w = tid >> 6;
  const int qsub = w & 3;
  const int p = w >> 2;
  const int q32 = lane & 31;
  const int hi = lane >> 5;
  const int xid = blockIdx.x & 7;
  const int lix = blockIdx.x >> 3;
  const int bh = xid * 4 + (lix & 3);
  const int bx = lix >> 2;
  const size_t kvbase = (size_t)bh * TT * 64;
  const int swz = q32 & 7;
  const int b = bh >> 4, h = bh & 15;

  const int srow = tid >> 3;
  const int scg = (tid & 7) ^ (srow & 7);
  const int sdst = w * 1024;

  for (int seg = 0; seg < 2; seg++) {
    const int qb = seg ? bx : 15 - bx;
    const int q0 = qb * 128;
    const int q0w = q0 + qsub * 32;
    const int ns = qb + 1;

    bf16x8 qf[4];
    {
      const short* qp = Qb + kvbase + (size_t)(q0w + q32) * 64;
#pragma unroll
      for (int kd = 0; kd < 4; kd++)
        qf[kd] = *(const bf16x8*)(qp + kd * 16 + hi * 8);
    }
    f32x16 accT[2];
#pragma unroll
    for (int i = 0; i < 16; i++) { accT[0][i] = 0.f; accT[1][i] = 0.f; }
    float m_run = -1e30f, l_run = 0.f;

#pragma unroll
    for (int t2 = 0; t2 < 2; t2++) {
      int kv0 = t2 * 64;
      gload_lds16(Kb + kvbase + (size_t)(kv0 + srow) * 64 + scg * 8,
                  (char*)Kls + t2 * 8192 + sdst);
      gload_lds16(Vt + kvbase + (size_t)srow * TT + kv0 + scg * 8,
                  (char*)Vls + t2 * 8192 + sdst);
    }
    asm volatile("s_waitcnt vmcnt(0)" ::: "memory");
    __builtin_amdgcn_s_barrier();
    __builtin_amdgcn_sched_barrier(0);

    for (int s = 0; s < ns; s++) {
      if (s + 1 < ns) {
        const int bp = ((s + 1) & 1) * 2;
#pragma unroll
        for (int t2 = 0; t2 < 2; t2++) {
          int kv0 = (2 * (s + 1) + t2) * 64;
          gload_lds16(Kb + kvbase + (size_t)(kv0 + srow) * 64 + scg * 8,
                      (char*)Kls + (bp + t2) * 8192 + sdst);
          gload_lds16(Vt + kvbase + (size_t)srow * TT + kv0 + scg * 8,
                      (char*)Vls + (bp + t2) * 8192 + sdst);
        }
      }
      const int kv0 = (2 * s + p) * 64;
      if (kv0 <= q0w + 31) {
        const char* Kbase = (const char*)Kls + (2 * (s & 1) + p) * 8192;
        const char* Vbase = (const char*)Vls + (2 * (s & 1) + p) * 8192;
        f32x16 sA, sB;
#pragma unroll
        for (int i = 0; i < 16; i++) { sA[i] = 0.f; sB[i] = 0.f; }
        __builtin_amdgcn_s_setprio(1);
#pragma unroll
        for (int kd = 0; kd < 4; kd++) {
          int coff = ((kd * 2 + hi) ^ swz) * 16;
          bf16x8 a0 = *(const bf16x8*)(Kbase + q32 * 128 + coff);
          bf16x8 a1 = *(const bf16x8*)(Kbase + (32 + q32) * 128 + coff);
          sA = __builtin_amdgcn_mfma_f32_32x32x16_bf16(a0, qf[kd], sA, 0, 0, 0);
          sB = __builtin_amdgcn_mfma_f32_32x32x16_bf16(a1, qf[kd], sB, 0, 0, 0);
        }
        __builtin_amdgcn_s_setprio(0);
        const int qg = q0w + q32;
        if (kv0 + 63 > q0w) {
#pragma unroll
          for (int r = 0; r < 16; r++) {
            int kvr = kv0 + (r & 3) + 8 * (r >> 2) + 4 * hi;
            if (kvr > qg) sA[r] = -1e30f;
            if (kvr + 32 > qg) sB[r] = -1e30f;
          }
        }
        float mx = sA[0];
#pragma unroll
        for (int r = 1; r < 16; r++) mx = fmaxf(mx, sA[r]);
#pragma unroll
        for (int r = 0; r < 16; r++) mx = fmaxf(mx, sB[r]);
        mx = fmaxf(mx, __shfl_xor(mx, 32));
        float mnew = fmaxf(m_run, mx);
        float corr = exp2f(m_run - mnew);
        float rs = 0.f;
#pragma unroll
        for (int r = 0; r < 16; r++) {
          sA[r] = exp2f(sA[r] - mnew);
          sB[r] = exp2f(sB[r] - mnew);
          rs += sA[r] + sB[r];
        }
        rs += __shfl_xor(rs, 32);
        l_run = l_run * corr + rs;
        m_run = mnew;
#pragma unroll
        for (int r = 0; r < 16; r++) { accT[0][r] *= corr; accT[1][r] *= corr; }

        bf16x8 pf[4];
#pragma unroll
        for (int t2 = 0; t2 < 2; t2++) {
#pragma unroll
          for (int s01 = 0; s01 < 2; s01++) {
            int base = 8 * s01;
            unsigned int wlo0, wlo1, whi0, whi1;
            if (t2 == 0) {
              wlo0 = cvt_pk_bf16(sA[base + 0], sA[base + 1]);
              wlo1 = cvt_pk_bf16(sA[base + 2], sA[base + 3]);
              whi0 = cvt_pk_bf16(sA[base + 4], sA[base + 5]);
              whi1 = cvt_pk_bf16(sA[base + 6], sA[base + 7]);
            } else {
              wlo0 = cvt_pk_bf16(sB[base + 0], sB[base + 1]);
              wlo1 = cvt_pk_bf16(sB[base + 2], sB[base + 3]);
              whi0 = cvt_pk_bf16(sB[base + 4], sB[base + 5]);
              whi1 = cvt_pk_bf16(sB[base + 6], sB[base + 7]);
            }
            asm volatile("v_permlane32_swap_b32 %0, %1" : "+v"(wlo0), "+v"(whi0));
            asm volatile("v_permlane32_swap_b32 %0, %1" : "+v"(wlo1), "+v"(whi1));
            union { unsigned int u[4]; bf16x8 v; } cc;
            cc.u[0] = wlo0; cc.u[1] = wlo1; cc.u[2] = whi0; cc.u[3] = whi1;
            pf[t2 * 2 + s01] = cc.v;
          }
        }
        __builtin_amdgcn_s_setprio(1);
#pragma unroll
        for (int db = 0; db < 2; db++) {
          const int row = db * 32 + q32;
#pragma unroll
          for (int ks = 0; ks < 4; ks++) {
            bf16x8 vf = *(const bf16x8*)(Vbase + row * 128 +
                                         (((ks * 2 + hi) ^ swz) * 16));
            accT[db] = __builtin_amdgcn_mfma_f32_32x32x16_bf16(vf, pf[ks],
                                                               accT[db], 0, 0, 0);
          }
        }
        __builtin_amdgcn_s_setprio(0);
      }
      asm volatile("s_waitcnt vmcnt(0) lgkmcnt(0)" ::: "memory");
      __builtin_amdgcn_s_barrier();
      __builtin_amdgcn_sched_barrier(0);
    }

    float* scrO = (float*)Kls;
    float* scrML = (float*)Vls;
    if (p == 1) {
#pragma unroll
      for (int db = 0; db < 2; db++)
#pragma unroll
        for (int r = 0; r < 16; r++)
          scrO[qsub * 2048 + (db * 16 + r) * 64 + lane] = accT[db][r];
      scrML[qsub * 64 + lane] = m_run;
      scrML[256 + qsub * 64 + lane] = l_run;
    }
    __syncthreads();
    if (p == 0) {
      float m_o = scrML[qsub * 64 + lane];
      float l_o = scrML[256 + qsub * 64 + lane];
      float mm = fmaxf(m_run, m_o);
      float ce = exp2f(m_run - mm), co = exp2f(m_o - mm);
      float lt = l_run * ce + l_o * co;
      float rinv = 1.f / lt;
      short* cp = Cb + (size_t)(b * TT + q0w + q32) * CDIM + h * 64;
#pragma unroll
      for (int db = 0; db < 2; db++)
#pragma unroll
        for (int rg = 0; rg < 4; rg++) {
          short4v pk4;
#pragma unroll
          for (int rr = 0; rr < 4; rr++) {
            int r = rg * 4 + rr;
            float v = accT[db][r] * ce +
                      scrO[qsub * 2048 + (db * 16 + r) * 64 + lane] * co;
            pk4[rr] = f2bf(v * rinv);
          }
          *(short4v*)(cp + db * 32 + rg * 8 + hi * 4) = pk4;
        }
    }
    __syncthreads();
  }
}

// ---------------------------------------------------------------------------
extern "C" void kernel_launch(void* const* d_in, const int* in_sizes, int n_in,
                              void* d_out, int out_size, void* d_ws, size_t ws_size,
                              hipStream_t stream) {
  const float* x       = (const float*)d_in[0];
  const float* W_attn  = (const float*)d_in[1];
  const float* b_attn  = (const float*)d_in[2];
  const float* A_attn  = (const float*)d_in[3];
  const float* B_attn  = (const float*)d_in[4];
  const float* W_proj  = (const float*)d_in[5];
  const float* b_proj  = (const float*)d_in[6];
  const float* A_proj  = (const float*)d_in[7];
  const float* B_proj  = (const float*)d_in[8];
  const float* kv_scale = (const float*)d_in[9];
  const float* kv_zp    = (const float*)d_in[10];
  float* out = (float*)d_out;

  char* p = (char*)d_ws;
  short* Xb    = (short*)p; p += (size_t)BT * CDIM * 2;
  short* Waug1 = (short*)p; p += (size_t)3072 * CDIM * 2;
  short* Waug2 = (short*)p; p += (size_t)1024 * CDIM * 2;
  short* Cb    = (short*)p; p += (size_t)BT * CDIM * 2;
  short* Qb    = (short*)p; p += (size_t)32 * TT * 64 * 2;
  short* Kb    = (short*)p; p += (size_t)32 * TT * 64 * 2;
  short* Vt    = (short*)p; p += (size_t)32 * TT * 64 * 2;

  packx_kernel<<<dim3(2048), dim3(256), 0, stream>>>(x, Xb);
  packw_eff_kernel<<<dim3(1536), dim3(256), 0, stream>>>(
      W_attn, B_attn, A_attn, Waug1);
  packw_eff_kernel<<<dim3(512), dim3(256), 0, stream>>>(
      W_proj, B_proj, A_proj, Waug2);
  gemm_qkv_kernel<<<dim3(768), dim3(256), 0, stream>>>(
      Xb, Waug1, b_attn, kv_scale, kv_zp, Qb, Kb, Vt);
  attn_kernel<<<dim3(256), dim3(512), 0, stream>>>(Qb, Kb, Vt, Cb);
  gemm_proj_kernel<<<dim3(256), dim3(256), 0, stream>>>(
      Cb, Waug2, b_proj, out);
}